// Round 7
// baseline (14593.706 us; speedup 1.0000x reference)
//
#include <hip/hip_runtime.h>

#define BATCH 64
#define TSTEPS 256
#define INDIM 512
#define HDIM 1024
#define NBLK 256
#define NTHR 1024
#define S0 48   // (512+1024)/32 k-steps, layer0
#define S1 64   // 2048/32, layer1
#define SF 32   // 1024/32, fc

typedef __bf16 bf16_t;
typedef __bf16 bf16x8 __attribute__((ext_vector_type(8)));
typedef float  f32x4  __attribute__((ext_vector_type(4)));

__device__ __forceinline__ float fast_sigmoid(float x){
  x = fminf(fmaxf(x, -30.f), 30.f);
  return 1.f / (1.f + __expf(-x));
}
__device__ __forceinline__ float fast_tanh(float x){
  x = fminf(fmaxf(x, -15.f), 15.f);
  float e = __expf(2.f * x);
  return (e - 1.f) / (e + 1.f);
}

// Flat distributed-flag barrier (R0-proven form; no cache fence needed since
// all cross-block data moves via agent-scope write-through atomics).
// 1024 threads poll 256 slots via (tid & 255). Watchdog bounds the poll so a
// sync failure surfaces as a fast absmax fail, not a GPU wedge.
__device__ __forceinline__ void grid_barrier(unsigned* arrive, unsigned target){
  asm volatile("s_waitcnt vmcnt(0)" ::: "memory");  // drain this wave's write-through stores
  __syncthreads();                                   // all 16 waves drained + LDS settled
  if (threadIdx.x == 0)
    __hip_atomic_store(&arrive[blockIdx.x * 16], target, __ATOMIC_RELAXED, __HIP_MEMORY_SCOPE_AGENT);
  unsigned* slot = &arrive[(threadIdx.x & 255) * 16];
  for (int it = 0; it < 20000; ++it){
    if (__hip_atomic_load(slot, __ATOMIC_RELAXED, __HIP_MEMORY_SCOPE_AGENT) >= target) break;
    __builtin_amdgcn_s_sleep(1);
  }
  __syncthreads();
}

__device__ __forceinline__ bf16x8 load_frag_wt(const bf16_t* p){
  // 16B A-fragment as 2x8B agent-scope loads (R0-proven coherence path).
  // These serialize per use (~600cy MALL RTT) — hidden by 4 waves/SIMD TLP,
  // which is the R7 change (k-split x4): chain length 48/64/32 -> 12/16/8.
  unsigned long long* q = (unsigned long long*)p;
  unsigned long long a0 = __hip_atomic_load(q,     __ATOMIC_RELAXED, __HIP_MEMORY_SCOPE_AGENT);
  unsigned long long a1 = __hip_atomic_load(q + 1, __ATOMIC_RELAXED, __HIP_MEMORY_SCOPE_AGENT);
  ulonglong2 av; av.x = a0; av.y = a1;
  return __builtin_bit_cast(bf16x8, av);
}

// K-window of the per-wave 16x16 GEMM: NSTEP k-steps starting at s_beg.
// A k-steps s<n1 come from p1, else p2. W from LDS in fragment order:
// W[(s*64 + lane)*8 + j] = Wcol[n=lane&15][k = s*32 + (lane>>4)*8 + j].
template<int NSTEP>
__device__ __forceinline__ void gemm_win(const bf16_t* p1, const bf16_t* p2,
                                         int n1, int s_beg,
                                         const bf16_t* Wl, int lane,
                                         f32x4& acc0, f32x4& acc1){
  const bf16_t* Wp = Wl + lane * 8;
#pragma unroll
  for (int j = 0; j < NSTEP; ++j){
    const int s = s_beg + j;
    const bf16_t* p = (s < n1) ? (p1 + s * 32) : (p2 + (s - n1) * 32);
    bf16x8 af = load_frag_wt(p);
    bf16x8 wf = *(const bf16x8*)(Wp + (size_t)s * 512);
    if (j & 1) acc1 = __builtin_amdgcn_mfma_f32_16x16x32_bf16(af, wf, acc1, 0, 0, 0);
    else       acc0 = __builtin_amdgcn_mfma_f32_16x16x32_bf16(af, wf, acc0, 0, 0, 0);
  }
}

// Persistent cooperative kernel: 256 blocks (1/CU) x 1024 threads (16 waves,
// 4 waves/SIMD). Block b owns hidden units {4b..4b+3} of both layers
// (16 gate cols each, LDS-resident bf16 weights), plus fc cols {16b..16b+15}
// for b<32. Wave w = (kq=w>>2, wv2=w&3): computes batch rows [16*wv2,+16) for
// K-quarter kq; partials reduced via LDS atomicAdd into gates_s (bias-seeded).
// 4 independent load-latency chains per SIMD overlap (TLP) — this attacks the
// measured bottleneck: serialized ~600cy MALL round-trips per k-step at
// 1 wave/SIMD (R0-R6: 10ms flat across three load-mechanism variants).
extern "C" __global__ void __launch_bounds__(NTHR, 4)
rnn_persistent(const float* __restrict__ hx,  const float* __restrict__ c0g,
               const float* __restrict__ Wih0, const float* __restrict__ Whh0,
               const float* __restrict__ bih0, const float* __restrict__ bhh0,
               const float* __restrict__ Wih1, const float* __restrict__ Whh1,
               const float* __restrict__ bih1, const float* __restrict__ bhh1,
               const float* __restrict__ fcw,  const float* __restrict__ fcb,
               float* __restrict__ out, void* ws)
{
  __shared__ bf16_t W0s[S0 * 512];        // 49152 B
  __shared__ bf16_t W1s[S1 * 512];        // 65536 B
  __shared__ bf16_t WFs[SF * 512];        // 32768 B
  __shared__ float  gates_s[4][16][17];   // bias-seeded accumulation target (+1 pad)
  __shared__ float  c0_l[BATCH][4];
  __shared__ float  c1_l[BATCH][4];
  __shared__ __align__(8) bf16_t hstage[BATCH][4];   // pack 4x bf16 -> one 8B store
  __shared__ __align__(8) bf16_t tstage[BATCH][16];  // fc slice staging (b<32)
  __shared__ float  b0_l[16];
  __shared__ float  b1_l[16];
  __shared__ float  bf_l[16];

  const int b    = blockIdx.x;
  const int tid  = threadIdx.x;
  const int lane = tid & 63;
  const int wv   = tid >> 6;        // 0..15
  const int wv2  = wv & 3;          // row-group (16 batch rows)
  const int kq   = wv >> 2;         // K-quarter
  const int q    = lane >> 4;
  const int nl   = lane & 15;

  unsigned* arrive = (unsigned*)ws;                  // 256 slots x 64B = 16KB (+pad to 32KB)
  bf16_t* token = (bf16_t*)((char*)ws + 32768);      // [64][512]
  bf16_t* h0b   = token + BATCH * INDIM;             // 2 x [64][1024]
  bf16_t* h1b   = h0b + 2 * BATCH * HDIM;            // 2 x [64][1024]

  // ---- init: swizzle this block's weight slice (fp32 -> bf16) into LDS ----
  // col for n_local: gate = nl>>2 (i,f,g,o), unit = 4b + (nl&3)
  for (int idx = tid; idx < S0 * 64; idx += NTHR){
    int s = idx >> 6, L = idx & 63;
    int qq = L >> 4, nn = L & 15;
    int col = (nn >> 2) * HDIM + b * 4 + (nn & 3);
    int k0 = s * 32 + qq * 8;
    const float* src = (k0 < INDIM) ? (Wih0 + col * INDIM + k0)
                                    : (Whh0 + col * HDIM + (k0 - INDIM));
    float4 u0 = ((const float4*)src)[0];
    float4 u1 = ((const float4*)src)[1];
    bf16_t* dst = W0s + idx * 8;
    dst[0]=(bf16_t)u0.x; dst[1]=(bf16_t)u0.y; dst[2]=(bf16_t)u0.z; dst[3]=(bf16_t)u0.w;
    dst[4]=(bf16_t)u1.x; dst[5]=(bf16_t)u1.y; dst[6]=(bf16_t)u1.z; dst[7]=(bf16_t)u1.w;
  }
  for (int idx = tid; idx < S1 * 64; idx += NTHR){
    int s = idx >> 6, L = idx & 63;
    int qq = L >> 4, nn = L & 15;
    int col = (nn >> 2) * HDIM + b * 4 + (nn & 3);
    int k0 = s * 32 + qq * 8;
    const float* src = (k0 < HDIM) ? (Wih1 + col * HDIM + k0)
                                   : (Whh1 + col * HDIM + (k0 - HDIM));
    float4 u0 = ((const float4*)src)[0];
    float4 u1 = ((const float4*)src)[1];
    bf16_t* dst = W1s + idx * 8;
    dst[0]=(bf16_t)u0.x; dst[1]=(bf16_t)u0.y; dst[2]=(bf16_t)u0.z; dst[3]=(bf16_t)u0.w;
    dst[4]=(bf16_t)u1.x; dst[5]=(bf16_t)u1.y; dst[6]=(bf16_t)u1.z; dst[7]=(bf16_t)u1.w;
  }
  if (b < 32){
    for (int idx = tid; idx < SF * 64; idx += NTHR){
      int s = idx >> 6, L = idx & 63;
      int qq = L >> 4, nn = L & 15;
      int col = b * 16 + nn;
      int k0 = s * 32 + qq * 8;
      const float* src = fcw + col * HDIM + k0;
      float4 u0 = ((const float4*)src)[0];
      float4 u1 = ((const float4*)src)[1];
      bf16_t* dst = WFs + idx * 8;
      dst[0]=(bf16_t)u0.x; dst[1]=(bf16_t)u0.y; dst[2]=(bf16_t)u0.z; dst[3]=(bf16_t)u0.w;
      dst[4]=(bf16_t)u1.x; dst[5]=(bf16_t)u1.y; dst[6]=(bf16_t)u1.z; dst[7]=(bf16_t)u1.w;
    }
    if (tid < 16) bf_l[tid] = fcb[b * 16 + tid];
  }
  if (tid < 16){
    int col = (tid >> 2) * HDIM + b * 4 + (tid & 3);
    b0_l[tid] = bih0[col] + bhh0[col];
    b1_l[tid] = bih1[col] + bhh1[col];
  }
  if (tid < 256){
    int row = tid & 63, uu = tid >> 6;
    int unit = b * 4 + uu;
    c0_l[row][uu] = c0g[row * HDIM + unit];
    c1_l[row][uu] = c0g[BATCH * HDIM + row * HDIM + unit];
  }
  if (tid < 64){
    int unit = b * 4;
    // initial h (parity 0) as packed 8B write-through stores
    float4 v0 = *(const float4*)(hx + tid * HDIM + unit);
    float4 v1 = *(const float4*)(hx + BATCH * HDIM + tid * HDIM + unit);
    bf16_t p0[4] = {(bf16_t)v0.x, (bf16_t)v0.y, (bf16_t)v0.z, (bf16_t)v0.w};
    bf16_t p1[4] = {(bf16_t)v1.x, (bf16_t)v1.y, (bf16_t)v1.z, (bf16_t)v1.w};
    __hip_atomic_store((unsigned long long*)(h0b + tid * HDIM + unit),
                       *(const unsigned long long*)p0, __ATOMIC_RELAXED, __HIP_MEMORY_SCOPE_AGENT);
    __hip_atomic_store((unsigned long long*)(h1b + tid * HDIM + unit),
                       *(const unsigned long long*)p1, __ATOMIC_RELAXED, __HIP_MEMORY_SCOPE_AGENT);
  }
  if (tid < 32){
    // token0 = zeros: block b zeroes its 256B slice (32 x 8B)
    __hip_atomic_store((unsigned long long*)(token + b * 128 + tid * 4), 0ull,
                       __ATOMIC_RELAXED, __HIP_MEMORY_SCOPE_AGENT);
  }
  __syncthreads();                       // b0_l ready for the seed below
  {
    // seed gates with layer-0 bias: 1024 threads == 4*16*16 cells exactly
    int g = tid >> 8, m = (tid >> 4) & 15, n = tid & 15;
    gates_s[g][m][n] = b0_l[n];
  }

  unsigned bargen = 1;
  grid_barrier(arrive, bargen++);

#pragma unroll 1
  for (int t = 0; t < TSTEPS; ++t){
    const int rp = t & 1, wp = rp ^ 1;
    const bf16_t* h0r = h0b + rp * BATCH * HDIM;
    bf16_t*       h0w = h0b + wp * BATCH * HDIM;
    const bf16_t* h1r = h1b + rp * BATCH * HDIM;
    bf16_t*       h1w = h1b + wp * BATCH * HDIM;
    const int arow = wv2 * 16 + nl;   // A-operand row for this lane (m = lane&15)

    // ---- phase 1: layer-0 gates (A = [token | h0_prev]) + cell update ----
    {
      f32x4 acc0 = {0.f,0.f,0.f,0.f}, acc1 = {0.f,0.f,0.f,0.f};
      gemm_win<12>(token + arow * INDIM + q * 8,
                   h0r   + arow * HDIM  + q * 8, 16, kq * 12, W0s, lane, acc0, acc1);
      f32x4 accv = acc0 + acc1;
#pragma unroll
      for (int r = 0; r < 4; ++r) atomicAdd(&gates_s[wv2][q * 4 + r][nl], accv[r]);
      __syncthreads();
      if (tid < 256){
        int row = tid & 63, uu = tid >> 6;
        float pi = gates_s[row >> 4][row & 15][0 * 4 + uu];
        float pf = gates_s[row >> 4][row & 15][1 * 4 + uu];
        float pg = gates_s[row >> 4][row & 15][2 * 4 + uu];
        float po = gates_s[row >> 4][row & 15][3 * 4 + uu];
        float ig = fast_sigmoid(pi), fg = fast_sigmoid(pf);
        float gg = fast_tanh(pg),    og = fast_sigmoid(po);
        float c  = fg * c0_l[row][uu] + ig * gg;
        c0_l[row][uu] = c;
        hstage[row][uu] = (bf16_t)(og * fast_tanh(c));
      }
      __syncthreads();
      {
        int g = tid >> 8, m = (tid >> 4) & 15, n = tid & 15;
        gates_s[g][m][n] = b1_l[n];          // seed for phase 2
      }
      if (tid < 64){
        unsigned long long v = *(const unsigned long long*)hstage[tid];
        __hip_atomic_store((unsigned long long*)(h0w + tid * HDIM + b * 4), v,
                           __ATOMIC_RELAXED, __HIP_MEMORY_SCOPE_AGENT);
      }
    }
    grid_barrier(arrive, bargen++);

    // ---- phase 2: layer-1 gates (A = [h0_new | h1_prev]) + cell update ----
    {
      f32x4 acc0 = {0.f,0.f,0.f,0.f}, acc1 = {0.f,0.f,0.f,0.f};
      gemm_win<16>(h0w + arow * HDIM + q * 8,
                   h1r + arow * HDIM + q * 8, 32, kq * 16, W1s, lane, acc0, acc1);
      f32x4 accv = acc0 + acc1;
#pragma unroll
      for (int r = 0; r < 4; ++r) atomicAdd(&gates_s[wv2][q * 4 + r][nl], accv[r]);
      __syncthreads();
      if (tid < 256){
        int row = tid & 63, uu = tid >> 6;
        float pi = gates_s[row >> 4][row & 15][0 * 4 + uu];
        float pf = gates_s[row >> 4][row & 15][1 * 4 + uu];
        float pg = gates_s[row >> 4][row & 15][2 * 4 + uu];
        float po = gates_s[row >> 4][row & 15][3 * 4 + uu];
        float ig = fast_sigmoid(pi), fg = fast_sigmoid(pf);
        float gg = fast_tanh(pg),    og = fast_sigmoid(po);
        float c  = fg * c1_l[row][uu] + ig * gg;
        c1_l[row][uu] = c;
        hstage[row][uu] = (bf16_t)(og * fast_tanh(c));
      }
      __syncthreads();
      {
        int g = tid >> 8, m = (tid >> 4) & 15, n = tid & 15;
        gates_s[g][m][n] = (b < 32) ? bf_l[n] : b0_l[n];  // seed: fc (b<32) or next-t phase 1
      }
      if (tid < 64){
        unsigned long long v = *(const unsigned long long*)hstage[tid];
        __hip_atomic_store((unsigned long long*)(h1w + tid * HDIM + b * 4), v,
                           __ATOMIC_RELAXED, __HIP_MEMORY_SCOPE_AGENT);
      }
    }
    grid_barrier(arrive, bargen++);

    // ---- phase 3: fc + sigmoid -> out[:,t,:] and next token (blocks 0..31) ----
    if (b < 32){
      f32x4 acc0 = {0.f,0.f,0.f,0.f}, acc1 = {0.f,0.f,0.f,0.f};
      gemm_win<8>(h1w + arow * HDIM + q * 8,
                  h1w + arow * HDIM + q * 8, 32, kq * 8, WFs, lane, acc0, acc1);
      f32x4 accv = acc0 + acc1;
#pragma unroll
      for (int r = 0; r < 4; ++r) atomicAdd(&gates_s[wv2][q * 4 + r][nl], accv[r]);
      __syncthreads();
      {
        // 1024 threads == 64 rows x 16 cols: finish fc, write out + tstage
        int m = tid >> 4, n = tid & 15;
        float v = fast_sigmoid(gates_s[m >> 4][m & 15][n]);
        out[m * (TSTEPS * INDIM) + t * INDIM + b * 16 + n] = v;  // plain store (harness-only)
        tstage[m][n] = (bf16_t)v;
      }
      __syncthreads();
      {
        int g = tid >> 8, m = (tid >> 4) & 15, n = tid & 15;
        gates_s[g][m][n] = b0_l[n];          // seed for next-t phase 1
      }
      if (tid < 256){
        int row = tid >> 2, part = tid & 3;
        unsigned long long v = *(const unsigned long long*)&tstage[row][part * 4];
        __hip_atomic_store((unsigned long long*)(token + row * INDIM + b * 16 + part * 4), v,
                           __ATOMIC_RELAXED, __HIP_MEMORY_SCOPE_AGENT);
      }
    }
    grid_barrier(arrive, bargen++);
  }
}

extern "C" void kernel_launch(void* const* d_in, const int* in_sizes, int n_in,
                              void* d_out, int out_size, void* d_ws, size_t ws_size,
                              hipStream_t stream){
  const float* hx   = (const float*)d_in[1];
  const float* c0g  = (const float*)d_in[2];
  const float* Wih0 = (const float*)d_in[3];
  const float* Whh0 = (const float*)d_in[4];
  const float* bih0 = (const float*)d_in[5];
  const float* bhh0 = (const float*)d_in[6];
  const float* Wih1 = (const float*)d_in[7];
  const float* Whh1 = (const float*)d_in[8];
  const float* bih1 = (const float*)d_in[9];
  const float* bhh1 = (const float*)d_in[10];
  const float* fcw  = (const float*)d_in[11];
  const float* fcb  = (const float*)d_in[12];
  float* out = (float*)d_out;

  // zero barrier flag slots (ws is poisoned 0xAA before every launch)
  hipMemsetAsync(d_ws, 0, 32768, stream);

  void* args[] = { (void*)&hx, (void*)&c0g, (void*)&Wih0, (void*)&Whh0,
                   (void*)&bih0, (void*)&bhh0, (void*)&Wih1, (void*)&Whh1,
                   (void*)&bih1, (void*)&bhh1, (void*)&fcw, (void*)&fcb,
                   (void*)&out, (void*)&d_ws };
  hipLaunchCooperativeKernel((const void*)rnn_persistent, dim3(NBLK), dim3(NTHR),
                             args, 0, stream);
}

// Round 8
// 10130.978 us; speedup vs baseline: 1.4405x; 1.4405x over previous
//
#include <hip/hip_runtime.h>

#define BATCH 64
#define TSTEPS 256
#define INDIM 512
#define HDIM 1024
#define NBLK 256
#define NTHR 256
#define S0 48   // (512+1024)/32 k-steps, layer0
#define S1 64   // 2048/32, layer1
#define SF 32   // 1024/32, fc

typedef __bf16 bf16_t;
typedef __bf16 bf16x8 __attribute__((ext_vector_type(8)));
typedef float  f32x4  __attribute__((ext_vector_type(4)));

__device__ __forceinline__ float fast_sigmoid(float x){
  x = fminf(fmaxf(x, -30.f), 30.f);
  return 1.f / (1.f + __expf(-x));
}
__device__ __forceinline__ float fast_tanh(float x){
  x = fminf(fmaxf(x, -15.f), 15.f);
  float e = __expf(2.f * x);
  return (e - 1.f) / (e + 1.f);
}

// Flat distributed-flag barrier: block b stores generation to its own 64B slot
// (write-through, agent scope, no RMW); thread i polls slot i. R0-proven.
// Watchdog bounds the poll (~5ms) so a sync failure surfaces as a fast absmax
// fail instead of a container-killing wedge (R6/R7-proven harmless).
__device__ __forceinline__ void grid_barrier(unsigned* arrive, unsigned target){
  asm volatile("s_waitcnt vmcnt(0)" ::: "memory");  // drain this wave's write-through stores
  __syncthreads();                                   // all waves drained + LDS settled
  if (threadIdx.x == 0)
    __hip_atomic_store(&arrive[blockIdx.x * 16], target, __ATOMIC_RELAXED, __HIP_MEMORY_SCOPE_AGENT);
  unsigned* slot = &arrive[threadIdx.x * 16];
  for (int it = 0; it < 20000; ++it){
    if (__hip_atomic_load(slot, __ATOMIC_RELAXED, __HIP_MEMORY_SCOPE_AGENT) >= target) break;
    __builtin_amdgcn_s_sleep(1);
  }
  __syncthreads();
}

__device__ __forceinline__ bf16x8 load_frag_wt(const bf16_t* p){
  // 16B A-fragment as 2x8B agent-scope loads (R0-proven coherence path).
  unsigned long long* q = (unsigned long long*)p;
  unsigned long long a0 = __hip_atomic_load(q,     __ATOMIC_RELAXED, __HIP_MEMORY_SCOPE_AGENT);
  unsigned long long a1 = __hip_atomic_load(q + 1, __ATOMIC_RELAXED, __HIP_MEMORY_SCOPE_AGENT);
  ulonglong2 av; av.x = a0; av.y = a1;
  return __builtin_bit_cast(bf16x8, av);
}

// One K-segment of the per-wave 16x16 GEMM, in GROUPS OF 8 k-steps:
// 8 agent-scope fragment loads issued back-to-back as straight-line NAMED
// scalars, then sched_barrier(0), then the 8 MFMAs. The barrier pins the
// machine scheduler: loads cannot sink to uses, MFMAs cannot hoist above.
// Because loads are intrinsic SSA defs (not inline asm), SIInsertWaitcnts
// emits counted vmcnt(N) per first use and RA handles copies correctly —
// none of the R2/R3 asm hazards. Result: ~8-16 MALL round trips in flight
// instead of 1 (the 10ms bottleneck: 144 serialized ~600cy round trips/step).
// W from LDS in fragment order:
// W[(s*64 + lane)*8 + j] = Wcol[n=lane&15][k = s*32 + (lane>>4)*8 + j].
template<int NS>
__device__ __forceinline__ void gemm_seg(const bf16_t* aptr, const bf16_t* Wl, int wOff, int lane,
                                         f32x4& acc0, f32x4& acc1){
  static_assert(NS % 8 == 0, "NS must be a multiple of 8");
  const bf16_t* Wp = Wl + lane * 8;
#pragma unroll
  for (int g = 0; g < NS / 8; ++g){
    const int s0 = g * 8;
    bf16x8 a0 = load_frag_wt(aptr + (s0 + 0) * 32);
    bf16x8 a1 = load_frag_wt(aptr + (s0 + 1) * 32);
    bf16x8 a2 = load_frag_wt(aptr + (s0 + 2) * 32);
    bf16x8 a3 = load_frag_wt(aptr + (s0 + 3) * 32);
    bf16x8 a4 = load_frag_wt(aptr + (s0 + 4) * 32);
    bf16x8 a5 = load_frag_wt(aptr + (s0 + 5) * 32);
    bf16x8 a6 = load_frag_wt(aptr + (s0 + 6) * 32);
    bf16x8 a7 = load_frag_wt(aptr + (s0 + 7) * 32);
    __builtin_amdgcn_sched_barrier(0);   // loads stay above; MFMAs stay below
    acc0 = __builtin_amdgcn_mfma_f32_16x16x32_bf16(a0, *(const bf16x8*)(Wp + (size_t)(wOff + s0 + 0) * 512), acc0, 0, 0, 0);
    acc1 = __builtin_amdgcn_mfma_f32_16x16x32_bf16(a1, *(const bf16x8*)(Wp + (size_t)(wOff + s0 + 1) * 512), acc1, 0, 0, 0);
    acc0 = __builtin_amdgcn_mfma_f32_16x16x32_bf16(a2, *(const bf16x8*)(Wp + (size_t)(wOff + s0 + 2) * 512), acc0, 0, 0, 0);
    acc1 = __builtin_amdgcn_mfma_f32_16x16x32_bf16(a3, *(const bf16x8*)(Wp + (size_t)(wOff + s0 + 3) * 512), acc1, 0, 0, 0);
    acc0 = __builtin_amdgcn_mfma_f32_16x16x32_bf16(a4, *(const bf16x8*)(Wp + (size_t)(wOff + s0 + 4) * 512), acc0, 0, 0, 0);
    acc1 = __builtin_amdgcn_mfma_f32_16x16x32_bf16(a5, *(const bf16x8*)(Wp + (size_t)(wOff + s0 + 5) * 512), acc1, 0, 0, 0);
    acc0 = __builtin_amdgcn_mfma_f32_16x16x32_bf16(a6, *(const bf16x8*)(Wp + (size_t)(wOff + s0 + 6) * 512), acc0, 0, 0, 0);
    acc1 = __builtin_amdgcn_mfma_f32_16x16x32_bf16(a7, *(const bf16x8*)(Wp + (size_t)(wOff + s0 + 7) * 512), acc1, 0, 0, 0);
  }
}

// Persistent cooperative kernel: 256 blocks (1/CU) x 256 threads (4 waves).
// Block b owns hidden units {4b..4b+3} of both layers (16 gate cols each,
// LDS-resident bf16 weights), plus fc cols {16b..16b+15} for b<32. Wave w
// computes batch rows [16w,16w+16) via mfma_f32_16x16x32_bf16. c-state fp32
// in LDS (never leaves block). R0 structure (best known: 10.05ms); R8 change
// is ONLY the grouped-load gemm_seg above.
extern "C" __global__ void __launch_bounds__(NTHR, 1)
rnn_persistent(const float* __restrict__ hx,  const float* __restrict__ c0g,
               const float* __restrict__ Wih0, const float* __restrict__ Whh0,
               const float* __restrict__ bih0, const float* __restrict__ bhh0,
               const float* __restrict__ Wih1, const float* __restrict__ Whh1,
               const float* __restrict__ bih1, const float* __restrict__ bhh1,
               const float* __restrict__ fcw,  const float* __restrict__ fcb,
               float* __restrict__ out, void* ws)
{
  __shared__ bf16_t W0s[S0 * 512];        // 49152 B
  __shared__ bf16_t W1s[S1 * 512];        // 65536 B
  __shared__ bf16_t WFs[SF * 512];        // 32768 B
  __shared__ float  gates_s[4][16][17];   // per-wave 16x16 gate staging (+1 pad)
  __shared__ float  c0_l[BATCH][4];
  __shared__ float  c1_l[BATCH][4];
  __shared__ __align__(8) bf16_t hstage[BATCH][4];   // pack 4x bf16 -> one 8B store
  __shared__ __align__(8) bf16_t tstage[BATCH][16];  // fc slice staging (b<32)
  __shared__ float  b0_l[16];
  __shared__ float  b1_l[16];
  __shared__ float  bf_l[16];

  const int b    = blockIdx.x;
  const int tid  = threadIdx.x;
  const int lane = tid & 63;
  const int wv   = tid >> 6;
  const int q    = lane >> 4;
  const int nl   = lane & 15;

  unsigned* arrive = (unsigned*)ws;                  // 256 slots x 64B = 16KB (+pad to 32KB)
  bf16_t* token = (bf16_t*)((char*)ws + 32768);      // [64][512]
  bf16_t* h0b   = token + BATCH * INDIM;             // 2 x [64][1024]
  bf16_t* h1b   = h0b + 2 * BATCH * HDIM;            // 2 x [64][1024]

  // ---- init: swizzle this block's weight slice (fp32 -> bf16) into LDS ----
  // col for n_local: gate = nl>>2 (i,f,g,o), unit = 4b + (nl&3)
  for (int idx = tid; idx < S0 * 64; idx += NTHR){
    int s = idx >> 6, L = idx & 63;
    int qq = L >> 4, nn = L & 15;
    int col = (nn >> 2) * HDIM + b * 4 + (nn & 3);
    int k0 = s * 32 + qq * 8;
    const float* src = (k0 < INDIM) ? (Wih0 + col * INDIM + k0)
                                    : (Whh0 + col * HDIM + (k0 - INDIM));
    float4 u0 = ((const float4*)src)[0];
    float4 u1 = ((const float4*)src)[1];
    bf16_t* dst = W0s + idx * 8;
    dst[0]=(bf16_t)u0.x; dst[1]=(bf16_t)u0.y; dst[2]=(bf16_t)u0.z; dst[3]=(bf16_t)u0.w;
    dst[4]=(bf16_t)u1.x; dst[5]=(bf16_t)u1.y; dst[6]=(bf16_t)u1.z; dst[7]=(bf16_t)u1.w;
  }
  for (int idx = tid; idx < S1 * 64; idx += NTHR){
    int s = idx >> 6, L = idx & 63;
    int qq = L >> 4, nn = L & 15;
    int col = (nn >> 2) * HDIM + b * 4 + (nn & 3);
    int k0 = s * 32 + qq * 8;
    const float* src = (k0 < HDIM) ? (Wih1 + col * HDIM + k0)
                                   : (Whh1 + col * HDIM + (k0 - HDIM));
    float4 u0 = ((const float4*)src)[0];
    float4 u1 = ((const float4*)src)[1];
    bf16_t* dst = W1s + idx * 8;
    dst[0]=(bf16_t)u0.x; dst[1]=(bf16_t)u0.y; dst[2]=(bf16_t)u0.z; dst[3]=(bf16_t)u0.w;
    dst[4]=(bf16_t)u1.x; dst[5]=(bf16_t)u1.y; dst[6]=(bf16_t)u1.z; dst[7]=(bf16_t)u1.w;
  }
  if (b < 32){
    for (int idx = tid; idx < SF * 64; idx += NTHR){
      int s = idx >> 6, L = idx & 63;
      int qq = L >> 4, nn = L & 15;
      int col = b * 16 + nn;
      int k0 = s * 32 + qq * 8;
      const float* src = fcw + col * HDIM + k0;
      float4 u0 = ((const float4*)src)[0];
      float4 u1 = ((const float4*)src)[1];
      bf16_t* dst = WFs + idx * 8;
      dst[0]=(bf16_t)u0.x; dst[1]=(bf16_t)u0.y; dst[2]=(bf16_t)u0.z; dst[3]=(bf16_t)u0.w;
      dst[4]=(bf16_t)u1.x; dst[5]=(bf16_t)u1.y; dst[6]=(bf16_t)u1.z; dst[7]=(bf16_t)u1.w;
    }
    if (tid < 16) bf_l[tid] = fcb[b * 16 + tid];
  }
  if (tid < 16){
    int col = (tid >> 2) * HDIM + b * 4 + (tid & 3);
    b0_l[tid] = bih0[col] + bhh0[col];
    b1_l[tid] = bih1[col] + bhh1[col];
  }
  {
    int row = tid & 63, uu = tid >> 6;
    int unit = b * 4 + uu;
    c0_l[row][uu] = c0g[row * HDIM + unit];
    c1_l[row][uu] = c0g[BATCH * HDIM + row * HDIM + unit];
  }
  if (tid < 64){
    int unit = b * 4;
    // initial h (parity 0) as packed 8B write-through stores
    float4 v0 = *(const float4*)(hx + tid * HDIM + unit);
    float4 v1 = *(const float4*)(hx + BATCH * HDIM + tid * HDIM + unit);
    bf16_t p0[4] = {(bf16_t)v0.x, (bf16_t)v0.y, (bf16_t)v0.z, (bf16_t)v0.w};
    bf16_t p1[4] = {(bf16_t)v1.x, (bf16_t)v1.y, (bf16_t)v1.z, (bf16_t)v1.w};
    __hip_atomic_store((unsigned long long*)(h0b + tid * HDIM + unit),
                       *(const unsigned long long*)p0, __ATOMIC_RELAXED, __HIP_MEMORY_SCOPE_AGENT);
    __hip_atomic_store((unsigned long long*)(h1b + tid * HDIM + unit),
                       *(const unsigned long long*)p1, __ATOMIC_RELAXED, __HIP_MEMORY_SCOPE_AGENT);
  }
  if (tid < 32){
    // token0 = zeros: block b zeroes its 256B slice (32 x 8B)
    __hip_atomic_store((unsigned long long*)(token + b * 128 + tid * 4), 0ull,
                       __ATOMIC_RELAXED, __HIP_MEMORY_SCOPE_AGENT);
  }

  unsigned bargen = 1;
  grid_barrier(arrive, bargen++);

#pragma unroll 1
  for (int t = 0; t < TSTEPS; ++t){
    const int rp = t & 1, wp = rp ^ 1;
    const bf16_t* h0r = h0b + rp * BATCH * HDIM;
    bf16_t*       h0w = h0b + wp * BATCH * HDIM;
    const bf16_t* h1r = h1b + rp * BATCH * HDIM;
    bf16_t*       h1w = h1b + wp * BATCH * HDIM;
    const int arow = wv * 16 + nl;   // A-operand row for this lane (m = lane&15)

    // ---- phase 1: layer-0 gates (A = [token | h0_prev]) + cell update ----
    {
      f32x4 acc0 = {0.f,0.f,0.f,0.f}, acc1 = {0.f,0.f,0.f,0.f};
      gemm_seg<16>(token + arow * INDIM + q * 8, W0s, 0,  lane, acc0, acc1);
      gemm_seg<32>(h0r   + arow * HDIM  + q * 8, W0s, 16, lane, acc0, acc1);
      f32x4 accv = acc0 + acc1;
      float bias = b0_l[nl];
#pragma unroll
      for (int r = 0; r < 4; ++r) gates_s[wv][q * 4 + r][nl] = accv[r] + bias;
      __syncthreads();
      int row = tid & 63, uu = tid >> 6;
      float pi = gates_s[row >> 4][row & 15][0 * 4 + uu];
      float pf = gates_s[row >> 4][row & 15][1 * 4 + uu];
      float pg = gates_s[row >> 4][row & 15][2 * 4 + uu];
      float po = gates_s[row >> 4][row & 15][3 * 4 + uu];
      float ig = fast_sigmoid(pi), fg = fast_sigmoid(pf);
      float gg = fast_tanh(pg),    og = fast_sigmoid(po);
      float c  = fg * c0_l[row][uu] + ig * gg;
      c0_l[row][uu] = c;
      hstage[row][uu] = (bf16_t)(og * fast_tanh(c));
      __syncthreads();
      if (tid < 64){
        unsigned long long v = *(const unsigned long long*)hstage[tid];
        __hip_atomic_store((unsigned long long*)(h0w + tid * HDIM + b * 4), v,
                           __ATOMIC_RELAXED, __HIP_MEMORY_SCOPE_AGENT);
      }
    }
    grid_barrier(arrive, bargen++);

    // ---- phase 2: layer-1 gates (A = [h0_new | h1_prev]) + cell update ----
    {
      f32x4 acc0 = {0.f,0.f,0.f,0.f}, acc1 = {0.f,0.f,0.f,0.f};
      gemm_seg<32>(h0w + arow * HDIM + q * 8, W1s, 0,  lane, acc0, acc1);
      gemm_seg<32>(h1r + arow * HDIM + q * 8, W1s, 32, lane, acc0, acc1);
      f32x4 accv = acc0 + acc1;
      float bias = b1_l[nl];
#pragma unroll
      for (int r = 0; r < 4; ++r) gates_s[wv][q * 4 + r][nl] = accv[r] + bias;
      __syncthreads();
      int row = tid & 63, uu = tid >> 6;
      float pi = gates_s[row >> 4][row & 15][0 * 4 + uu];
      float pf = gates_s[row >> 4][row & 15][1 * 4 + uu];
      float pg = gates_s[row >> 4][row & 15][2 * 4 + uu];
      float po = gates_s[row >> 4][row & 15][3 * 4 + uu];
      float ig = fast_sigmoid(pi), fg = fast_sigmoid(pf);
      float gg = fast_tanh(pg),    og = fast_sigmoid(po);
      float c  = fg * c1_l[row][uu] + ig * gg;
      c1_l[row][uu] = c;
      hstage[row][uu] = (bf16_t)(og * fast_tanh(c));
      __syncthreads();
      if (tid < 64){
        unsigned long long v = *(const unsigned long long*)hstage[tid];
        __hip_atomic_store((unsigned long long*)(h1w + tid * HDIM + b * 4), v,
                           __ATOMIC_RELAXED, __HIP_MEMORY_SCOPE_AGENT);
      }
    }
    grid_barrier(arrive, bargen++);

    // ---- phase 3: fc + sigmoid -> out[:,t,:] and next token (blocks 0..31) ----
    if (b < 32){
      f32x4 acc0 = {0.f,0.f,0.f,0.f}, acc1 = {0.f,0.f,0.f,0.f};
      gemm_seg<32>(h1w + arow * HDIM + q * 8, WFs, 0, lane, acc0, acc1);
      f32x4 accv = acc0 + acc1;
      int col = b * 16 + nl;
      float bias = bf_l[nl];
#pragma unroll
      for (int r = 0; r < 4; ++r){
        int m = wv * 16 + q * 4 + r;     // C/D: row = (lane>>4)*4 + reg, col = lane&15
        float v = fast_sigmoid(accv[r] + bias);
        out[m * (TSTEPS * INDIM) + t * INDIM + col] = v;   // plain store (harness-only)
        tstage[m][nl] = (bf16_t)v;
      }
      __syncthreads();
      {
        int row = tid >> 2, part = tid & 3;
        unsigned long long v = *(const unsigned long long*)&tstage[row][part * 4];
        __hip_atomic_store((unsigned long long*)(token + row * INDIM + b * 16 + part * 4), v,
                           __ATOMIC_RELAXED, __HIP_MEMORY_SCOPE_AGENT);
      }
    }
    grid_barrier(arrive, bargen++);
  }
}

extern "C" void kernel_launch(void* const* d_in, const int* in_sizes, int n_in,
                              void* d_out, int out_size, void* d_ws, size_t ws_size,
                              hipStream_t stream){
  const float* hx   = (const float*)d_in[1];
  const float* c0g  = (const float*)d_in[2];
  const float* Wih0 = (const float*)d_in[3];
  const float* Whh0 = (const float*)d_in[4];
  const float* bih0 = (const float*)d_in[5];
  const float* bhh0 = (const float*)d_in[6];
  const float* Wih1 = (const float*)d_in[7];
  const float* Whh1 = (const float*)d_in[8];
  const float* bih1 = (const float*)d_in[9];
  const float* bhh1 = (const float*)d_in[10];
  const float* fcw  = (const float*)d_in[11];
  const float* fcb  = (const float*)d_in[12];
  float* out = (float*)d_out;

  // zero barrier flag slots (ws is poisoned 0xAA before every launch)
  hipMemsetAsync(d_ws, 0, 32768, stream);

  void* args[] = { (void*)&hx, (void*)&c0g, (void*)&Wih0, (void*)&Whh0,
                   (void*)&bih0, (void*)&bhh0, (void*)&Wih1, (void*)&Whh1,
                   (void*)&bih1, (void*)&bhh1, (void*)&fcw, (void*)&fcb,
                   (void*)&out, (void*)&d_ws };
  hipLaunchCooperativeKernel((const void*)rnn_persistent, dim3(NBLK), dim3(NTHR),
                             args, 0, stream);
}

// Round 9
// 9373.695 us; speedup vs baseline: 1.5569x; 1.0808x over previous
//
#include <hip/hip_runtime.h>

#define BATCH 64
#define TSTEPS 256
#define INDIM 512
#define HDIM 1024
#define NBLK 256
#define NTHR 256
#define S0 48   // (512+1024)/32 k-steps, layer0
#define S1 64   // 2048/32, layer1

typedef __bf16 bf16_t;
typedef __bf16 bf16x8 __attribute__((ext_vector_type(8)));
typedef float  f32x4  __attribute__((ext_vector_type(4)));

// address-space-qualified casts for global_load_lds
typedef const __attribute__((address_space(1))) void gas_t;
typedef __attribute__((address_space(3))) void las_t;
#define GLOAD_LDS16(g, l) \
  __builtin_amdgcn_global_load_lds((gas_t*)(g), (las_t*)(l), 16, 0, 0)

__device__ __forceinline__ float fast_sigmoid(float x){
  x = fminf(fmaxf(x, -30.f), 30.f);
  return 1.f / (1.f + __expf(-x));
}
__device__ __forceinline__ float fast_tanh(float x){
  x = fminf(fmaxf(x, -15.f), 15.f);
  float e = __expf(2.f * x);
  return (e - 1.f) / (e + 1.f);
}

template<int N>
__device__ __forceinline__ void wait_vmcnt(){
  asm volatile("s_waitcnt vmcnt(%0)" :: "n"(N) : "memory");
}

// Flat distributed-flag barrier + ACQUIRE fence (R6-validated combo).
// Stores to shared ws state are agent-scope write-through atomics; the fence
// after the poll invalidates clean L1/L2 lines so the phase body's CACHED
// global_load_lds DMAs refetch fresh data from MALL on first touch.
// Watchdog bounds the poll (~5ms): sync failure -> fast absmax fail, no wedge.
__device__ __forceinline__ void grid_barrier(unsigned* arrive, unsigned target){
  asm volatile("s_waitcnt vmcnt(0)" ::: "memory");  // drain write-through stores
  __syncthreads();
  if (threadIdx.x == 0)
    __hip_atomic_store(&arrive[blockIdx.x * 16], target, __ATOMIC_RELAXED, __HIP_MEMORY_SCOPE_AGENT);
  unsigned* slot = &arrive[threadIdx.x * 16];
  for (int it = 0; it < 20000; ++it){
    if (__hip_atomic_load(slot, __ATOMIC_RELAXED, __HIP_MEMORY_SCOPE_AGENT) >= target) break;
    __builtin_amdgcn_s_sleep(1);
  }
  __builtin_amdgcn_fence(__ATOMIC_ACQUIRE, "agent");  // buffer_inv
  __syncthreads();
}

// ---------------------------------------------------------------------------
// Pipelined phase GEMM via global_load_lds (the anti-sinking mechanism: DMA
// has no VGPR destination, so the compiler CANNOT serialize it to one load
// in flight — the failure mode of R0/R6/R8 where every VGPR-destined load
// was re-sunk to its use, leaving 144 serialized ~600cy round trips/step).
//
// A-panel is streamed in 64-col tiles (2 k-steps). Per tile, wave w stages
// its 16 rows (2KB) with TWO width-16 DMAs into Abuf[buf][w]; triple buffer,
// prefetch distance 3, counted vmcnt(4/2/0) per tile (T3/T4).
//
// LDS tile layout: [16 rows][128B], XOR-swizzled: LDS[r][cb] holds
// A[r][cb ^ ((r&7)<<4)] — achieved by pre-swizzling the per-lane GLOBAL
// source address (DMA dest must stay linear, rule #21/m173). Stage lane l:
// row_local = 8j + (l>>3), dest colb=(l&7)*16, src colb = ((l&7)^(l>>3))<<4.
// Reader lane (q=lane>>4, nl=lane&15), k-step sl: byte addr =
// nl*128 + ((sl*64 + q*16) ^ ((nl&7)<<4)) — 16 lanes spread over 8 slots
// (2-way = free) instead of 16-way conflict.
// ---------------------------------------------------------------------------
#define STAGE_TILE(J, BUF)                                                     \
  {                                                                            \
    const char* base_; int rb_, cb0_;                                          \
    if ((J) < NT1){ base_ = p1; rb_ = rb1; cb0_ = (J) * 128; }                 \
    else          { base_ = p2; rb_ = rb2; cb0_ = ((J) - NT1) * 128; }         \
    const char* g_ = base_ + (size_t)(16 * wv + rl) * rb_ + cb0_ + scb;        \
    char* d_ = ab0 + (BUF) * 8192;                                             \
    GLOAD_LDS16(g_, d_);                                                       \
    GLOAD_LDS16(g_ + (size_t)8 * rb_, d_ + 1024);                              \
  }

template<int NT1, int NT2>
__device__ __forceinline__ void gemm_phase(const char* p1, int rb1,
                                           const char* p2, int rb2,
                                           const bf16_t* Wl, char* ab0,
                                           int wv, int lane, int q, int nl,
                                           f32x4& acc0, f32x4& acc1){
  constexpr int NT = NT1 + NT2;
  const int rl  = lane >> 3;
  const int scb = ((lane & 7) ^ rl) << 4;
  const int swz = (nl & 7) << 4;

  STAGE_TILE(0, 0); STAGE_TILE(1, 1); STAGE_TILE(2, 2);
#pragma unroll
  for (int i = 0; i < NT; ++i){
    if      (i + 2 < NT) wait_vmcnt<4>();   // tile i landed; i+1,i+2 in flight
    else if (i + 1 < NT) wait_vmcnt<2>();
    else                 wait_vmcnt<0>();
    __builtin_amdgcn_sched_barrier(0);
    const char* aw = ab0 + (i % 3) * 8192;
    bf16x8 a0 = *(const bf16x8*)(aw + nl * 128 + ((     q * 16) ^ swz));
    bf16x8 a1 = *(const bf16x8*)(aw + nl * 128 + ((64 + q * 16) ^ swz));
    bf16x8 w0 = *(const bf16x8*)(Wl + (size_t)(2 * i    ) * 512 + lane * 8);
    bf16x8 w1 = *(const bf16x8*)(Wl + (size_t)(2 * i + 1) * 512 + lane * 8);
    acc0 = __builtin_amdgcn_mfma_f32_16x16x32_bf16(a0, w0, acc0, 0, 0, 0);
    acc1 = __builtin_amdgcn_mfma_f32_16x16x32_bf16(a1, w1, acc1, 0, 0, 0);
    __builtin_amdgcn_sched_barrier(0);      // DMA below must not pass ds_reads
    if (i + 3 < NT) STAGE_TILE(i + 3, i % 3);  // refill just-consumed buffer
  }
}

// fc variant: W fragments live in 32 bf16x8 REGISTERS (preloaded at init;
// statically indexed under full unroll -> stays in VGPRs, rule #20).
template<int NT1>
__device__ __forceinline__ void fc_phase(const char* p1, int rb1,
                                         const bf16x8* wfc, char* ab0,
                                         int wv, int lane, int q, int nl,
                                         f32x4& acc0, f32x4& acc1){
  constexpr int NT = NT1;
  constexpr int NT2 = 0;
  const char* p2 = p1; const int rb2 = rb1;
  const int rl  = lane >> 3;
  const int scb = ((lane & 7) ^ rl) << 4;
  const int swz = (nl & 7) << 4;

  STAGE_TILE(0, 0); STAGE_TILE(1, 1); STAGE_TILE(2, 2);
#pragma unroll
  for (int i = 0; i < NT; ++i){
    if      (i + 2 < NT) wait_vmcnt<4>();
    else if (i + 1 < NT) wait_vmcnt<2>();
    else                 wait_vmcnt<0>();
    __builtin_amdgcn_sched_barrier(0);
    const char* aw = ab0 + (i % 3) * 8192;
    bf16x8 a0 = *(const bf16x8*)(aw + nl * 128 + ((     q * 16) ^ swz));
    bf16x8 a1 = *(const bf16x8*)(aw + nl * 128 + ((64 + q * 16) ^ swz));
    acc0 = __builtin_amdgcn_mfma_f32_16x16x32_bf16(a0, wfc[2 * i    ], acc0, 0, 0, 0);
    acc1 = __builtin_amdgcn_mfma_f32_16x16x32_bf16(a1, wfc[2 * i + 1], acc1, 0, 0, 0);
    __builtin_amdgcn_sched_barrier(0);
    if (i + 3 < NT) STAGE_TILE(i + 3, i % 3);
  }
}

// Persistent cooperative kernel: 256 blocks (1/CU) x 256 threads (4 waves).
// Block b owns hidden units {4b..4b+3} of both layers (16 gate cols each,
// LDS-resident bf16 weights), plus fc cols {16b..16b+15} for b<32 (fc weights
// in registers). Wave w computes batch rows [16w,16w+16). c-state in LDS.
extern "C" __global__ void __launch_bounds__(NTHR, 1)
rnn_persistent(const float* __restrict__ hx,  const float* __restrict__ c0g,
               const float* __restrict__ Wih0, const float* __restrict__ Whh0,
               const float* __restrict__ bih0, const float* __restrict__ bhh0,
               const float* __restrict__ Wih1, const float* __restrict__ Whh1,
               const float* __restrict__ bih1, const float* __restrict__ bhh1,
               const float* __restrict__ fcw,  const float* __restrict__ fcb,
               float* __restrict__ out, void* ws)
{
  __shared__ bf16_t W0s[S0 * 512];          // 49152 B
  __shared__ bf16_t W1s[S1 * 512];          // 65536 B
  __shared__ bf16_t Abuf[3][4][1024];       // 24576 B: 3 bufs x 4 waves x 2KB
  __shared__ float  gates_s[4][16][17];     // 4352 B
  __shared__ float  c0_l[BATCH][4];
  __shared__ float  c1_l[BATCH][4];
  __shared__ __align__(8) bf16_t hstage[BATCH][4];
  __shared__ __align__(8) bf16_t tstage[BATCH][16];
  __shared__ float  b0_l[16];
  __shared__ float  b1_l[16];
  __shared__ float  bf_l[16];

  const int b    = blockIdx.x;
  const int tid  = threadIdx.x;
  const int lane = tid & 63;
  const int wv   = tid >> 6;
  const int q    = lane >> 4;
  const int nl   = lane & 15;

  unsigned* arrive = (unsigned*)ws;                  // 256 slots x 64B
  bf16_t* token = (bf16_t*)((char*)ws + 32768);      // [64][512]
  bf16_t* h0b   = token + BATCH * INDIM;             // 2 x [64][1024]
  bf16_t* h1b   = h0b + 2 * BATCH * HDIM;            // 2 x [64][1024]

  char* ab0 = (char*)&Abuf[0][wv][0];                // wave's buf-0 region

  // ---- init: swizzle this block's weight slice (fp32 -> bf16) into LDS ----
  for (int idx = tid; idx < S0 * 64; idx += NTHR){
    int s = idx >> 6, L = idx & 63;
    int qq = L >> 4, nn = L & 15;
    int col = (nn >> 2) * HDIM + b * 4 + (nn & 3);
    int k0 = s * 32 + qq * 8;
    const float* src = (k0 < INDIM) ? (Wih0 + col * INDIM + k0)
                                    : (Whh0 + col * HDIM + (k0 - INDIM));
    float4 u0 = ((const float4*)src)[0];
    float4 u1 = ((const float4*)src)[1];
    bf16_t* dst = W0s + idx * 8;
    dst[0]=(bf16_t)u0.x; dst[1]=(bf16_t)u0.y; dst[2]=(bf16_t)u0.z; dst[3]=(bf16_t)u0.w;
    dst[4]=(bf16_t)u1.x; dst[5]=(bf16_t)u1.y; dst[6]=(bf16_t)u1.z; dst[7]=(bf16_t)u1.w;
  }
  for (int idx = tid; idx < S1 * 64; idx += NTHR){
    int s = idx >> 6, L = idx & 63;
    int qq = L >> 4, nn = L & 15;
    int col = (nn >> 2) * HDIM + b * 4 + (nn & 3);
    int k0 = s * 32 + qq * 8;
    const float* src = (k0 < HDIM) ? (Wih1 + col * HDIM + k0)
                                   : (Whh1 + col * HDIM + (k0 - HDIM));
    float4 u0 = ((const float4*)src)[0];
    float4 u1 = ((const float4*)src)[1];
    bf16_t* dst = W1s + idx * 8;
    dst[0]=(bf16_t)u0.x; dst[1]=(bf16_t)u0.y; dst[2]=(bf16_t)u0.z; dst[3]=(bf16_t)u0.w;
    dst[4]=(bf16_t)u1.x; dst[5]=(bf16_t)u1.y; dst[6]=(bf16_t)u1.z; dst[7]=(bf16_t)u1.w;
  }
  // fc weights -> registers (b<32 blocks use them; statically indexed)
  bf16x8 wfc[32];
  if (b < 32){
    const float* basew = fcw + (size_t)(b * 16 + nl) * HDIM + q * 8;
#pragma unroll
    for (int s = 0; s < 32; ++s){
      float4 u0 = *(const float4*)(basew + s * 32);
      float4 u1 = *(const float4*)(basew + s * 32 + 4);
      bf16_t t8[8] = {(bf16_t)u0.x,(bf16_t)u0.y,(bf16_t)u0.z,(bf16_t)u0.w,
                      (bf16_t)u1.x,(bf16_t)u1.y,(bf16_t)u1.z,(bf16_t)u1.w};
      wfc[s] = *(const bf16x8*)t8;
    }
    if (tid < 16) bf_l[tid] = fcb[b * 16 + tid];
  }
  if (tid < 16){
    int col = (tid >> 2) * HDIM + b * 4 + (tid & 3);
    b0_l[tid] = bih0[col] + bhh0[col];
    b1_l[tid] = bih1[col] + bhh1[col];
  }
  {
    int row = tid & 63, uu = tid >> 6;
    int unit = b * 4 + uu;
    c0_l[row][uu] = c0g[row * HDIM + unit];
    c1_l[row][uu] = c0g[BATCH * HDIM + row * HDIM + unit];
  }
  if (tid < 64){
    int unit = b * 4;
    float4 v0 = *(const float4*)(hx + tid * HDIM + unit);
    float4 v1 = *(const float4*)(hx + BATCH * HDIM + tid * HDIM + unit);
    bf16_t p0[4] = {(bf16_t)v0.x, (bf16_t)v0.y, (bf16_t)v0.z, (bf16_t)v0.w};
    bf16_t p1[4] = {(bf16_t)v1.x, (bf16_t)v1.y, (bf16_t)v1.z, (bf16_t)v1.w};
    __hip_atomic_store((unsigned long long*)(h0b + tid * HDIM + unit),
                       *(const unsigned long long*)p0, __ATOMIC_RELAXED, __HIP_MEMORY_SCOPE_AGENT);
    __hip_atomic_store((unsigned long long*)(h1b + tid * HDIM + unit),
                       *(const unsigned long long*)p1, __ATOMIC_RELAXED, __HIP_MEMORY_SCOPE_AGENT);
  }
  if (tid < 32){
    __hip_atomic_store((unsigned long long*)(token + b * 128 + tid * 4), 0ull,
                       __ATOMIC_RELAXED, __HIP_MEMORY_SCOPE_AGENT);
  }

  unsigned bargen = 1;
  grid_barrier(arrive, bargen++);

#pragma unroll 1
  for (int t = 0; t < TSTEPS; ++t){
    const int rp = t & 1, wp = rp ^ 1;
    const bf16_t* h0r = h0b + rp * BATCH * HDIM;
    bf16_t*       h0w = h0b + wp * BATCH * HDIM;
    const bf16_t* h1r = h1b + rp * BATCH * HDIM;
    bf16_t*       h1w = h1b + wp * BATCH * HDIM;

    // ---- phase 1: layer-0 gates (A = [token | h0_prev]) + cell update ----
    {
      f32x4 acc0 = {0.f,0.f,0.f,0.f}, acc1 = {0.f,0.f,0.f,0.f};
      gemm_phase<8, 16>((const char*)token, 1024,
                        (const char*)h0r,   2048,
                        W0s, ab0, wv, lane, q, nl, acc0, acc1);
      f32x4 accv = acc0 + acc1;
      float bias = b0_l[nl];
#pragma unroll
      for (int r = 0; r < 4; ++r) gates_s[wv][q * 4 + r][nl] = accv[r] + bias;
      __syncthreads();
      int row = tid & 63, uu = tid >> 6;
      float pi = gates_s[row >> 4][row & 15][0 * 4 + uu];
      float pf = gates_s[row >> 4][row & 15][1 * 4 + uu];
      float pg = gates_s[row >> 4][row & 15][2 * 4 + uu];
      float po = gates_s[row >> 4][row & 15][3 * 4 + uu];
      float ig = fast_sigmoid(pi), fg = fast_sigmoid(pf);
      float gg = fast_tanh(pg),    og = fast_sigmoid(po);
      float c  = fg * c0_l[row][uu] + ig * gg;
      c0_l[row][uu] = c;
      hstage[row][uu] = (bf16_t)(og * fast_tanh(c));
      __syncthreads();
      if (tid < 64){
        unsigned long long v = *(const unsigned long long*)hstage[tid];
        __hip_atomic_store((unsigned long long*)(h0w + tid * HDIM + b * 4), v,
                           __ATOMIC_RELAXED, __HIP_MEMORY_SCOPE_AGENT);
      }
    }
    grid_barrier(arrive, bargen++);

    // ---- phase 2: layer-1 gates (A = [h0_new | h1_prev]) + cell update ----
    {
      f32x4 acc0 = {0.f,0.f,0.f,0.f}, acc1 = {0.f,0.f,0.f,0.f};
      gemm_phase<16, 16>((const char*)h0w, 2048,
                         (const char*)h1r, 2048,
                         W1s, ab0, wv, lane, q, nl, acc0, acc1);
      f32x4 accv = acc0 + acc1;
      float bias = b1_l[nl];
#pragma unroll
      for (int r = 0; r < 4; ++r) gates_s[wv][q * 4 + r][nl] = accv[r] + bias;
      __syncthreads();
      int row = tid & 63, uu = tid >> 6;
      float pi = gates_s[row >> 4][row & 15][0 * 4 + uu];
      float pf = gates_s[row >> 4][row & 15][1 * 4 + uu];
      float pg = gates_s[row >> 4][row & 15][2 * 4 + uu];
      float po = gates_s[row >> 4][row & 15][3 * 4 + uu];
      float ig = fast_sigmoid(pi), fg = fast_sigmoid(pf);
      float gg = fast_tanh(pg),    og = fast_sigmoid(po);
      float c  = fg * c1_l[row][uu] + ig * gg;
      c1_l[row][uu] = c;
      hstage[row][uu] = (bf16_t)(og * fast_tanh(c));
      __syncthreads();
      if (tid < 64){
        unsigned long long v = *(const unsigned long long*)hstage[tid];
        __hip_atomic_store((unsigned long long*)(h1w + tid * HDIM + b * 4), v,
                           __ATOMIC_RELAXED, __HIP_MEMORY_SCOPE_AGENT);
      }
    }
    grid_barrier(arrive, bargen++);

    // ---- phase 3: fc + sigmoid -> out[:,t,:] and next token (blocks 0..31) ----
    if (b < 32){
      f32x4 acc0 = {0.f,0.f,0.f,0.f}, acc1 = {0.f,0.f,0.f,0.f};
      fc_phase<16>((const char*)h1w, 2048, wfc, ab0, wv, lane, q, nl, acc0, acc1);
      f32x4 accv = acc0 + acc1;
      int col = b * 16 + nl;
      float bias = bf_l[nl];
#pragma unroll
      for (int r = 0; r < 4; ++r){
        int m = wv * 16 + q * 4 + r;     // C/D: row = (lane>>4)*4 + reg, col = lane&15
        float v = fast_sigmoid(accv[r] + bias);
        out[m * (TSTEPS * INDIM) + t * INDIM + col] = v;
        tstage[m][nl] = (bf16_t)v;
      }
      __syncthreads();
      {
        int row = tid >> 2, part = tid & 3;
        unsigned long long v = *(const unsigned long long*)&tstage[row][part * 4];
        __hip_atomic_store((unsigned long long*)(token + row * INDIM + b * 16 + part * 4), v,
                           __ATOMIC_RELAXED, __HIP_MEMORY_SCOPE_AGENT);
      }
    }
    grid_barrier(arrive, bargen++);
  }
}

extern "C" void kernel_launch(void* const* d_in, const int* in_sizes, int n_in,
                              void* d_out, int out_size, void* d_ws, size_t ws_size,
                              hipStream_t stream){
  const float* hx   = (const float*)d_in[1];
  const float* c0g  = (const float*)d_in[2];
  const float* Wih0 = (const float*)d_in[3];
  const float* Whh0 = (const float*)d_in[4];
  const float* bih0 = (const float*)d_in[5];
  const float* bhh0 = (const float*)d_in[6];
  const float* Wih1 = (const float*)d_in[7];
  const float* Whh1 = (const float*)d_in[8];
  const float* bih1 = (const float*)d_in[9];
  const float* bhh1 = (const float*)d_in[10];
  const float* fcw  = (const float*)d_in[11];
  const float* fcb  = (const float*)d_in[12];
  float* out = (float*)d_out;

  // zero barrier flag slots (ws is poisoned 0xAA before every launch)
  hipMemsetAsync(d_ws, 0, 32768, stream);

  void* args[] = { (void*)&hx, (void*)&c0g, (void*)&Wih0, (void*)&Whh0,
                   (void*)&bih0, (void*)&bhh0, (void*)&Wih1, (void*)&Whh1,
                   (void*)&bih1, (void*)&bhh1, (void*)&fcw, (void*)&fcb,
                   (void*)&out, (void*)&d_ws };
  hipLaunchCooperativeKernel((const void*)rnn_persistent, dim3(NBLK), dim3(NTHR),
                             args, 0, stream);
}

// Round 10
// 6984.396 us; speedup vs baseline: 2.0895x; 1.3421x over previous
//
#include <hip/hip_runtime.h>

#define BATCH 64
#define TSTEPS 256
#define INDIM 512
#define HDIM 1024
#define NBLK 256
#define NTHR 256
#define S0 48   // (512+1024)/32 k-steps, layer0
#define S1 64   // 2048/32, layer1

typedef __bf16 bf16_t;
typedef __bf16 bf16x8 __attribute__((ext_vector_type(8)));
typedef float  f32x4  __attribute__((ext_vector_type(4)));

typedef const __attribute__((address_space(1))) void gas_t;
typedef __attribute__((address_space(3))) void las_t;
#define GLOAD_LDS16(g, l) \
  __builtin_amdgcn_global_load_lds((gas_t*)(g), (las_t*)(l), 16, 0, 0)

__device__ __forceinline__ float fast_sigmoid(float x){
  x = fminf(fmaxf(x, -30.f), 30.f);
  return 1.f / (1.f + __expf(-x));
}
__device__ __forceinline__ float fast_tanh(float x){
  x = fminf(fmaxf(x, -15.f), 15.f);
  float e = __expf(2.f * x);
  return (e - 1.f) / (e + 1.f);
}

template<int N>
__device__ __forceinline__ void wait_vmcnt(){
  asm volatile("s_waitcnt vmcnt(%0)" :: "n"(N) : "memory");
}

// ---- split grid barrier (R10): arrive early, wait late -------------------
// arrive: drain this block's write-through stores, then publish generation.
// wait: poll own slot, acquire-fence (buffer_inv) so cached reads of the
// published data are fresh. Between a block's arrive and its wait it runs
// GEMM halves whose inputs are one-generation old (already fenced) — this
// hides the barrier round trip under legal compute.
__device__ __forceinline__ void bar_arrive(unsigned* arrive, unsigned target){
  asm volatile("s_waitcnt vmcnt(0)" ::: "memory");
  __syncthreads();
  if (threadIdx.x == 0)
    __hip_atomic_store(&arrive[blockIdx.x * 16], target, __ATOMIC_RELAXED, __HIP_MEMORY_SCOPE_AGENT);
}
__device__ __forceinline__ void bar_wait(unsigned* arrive, unsigned target){
  unsigned* slot = &arrive[threadIdx.x * 16];
  for (int it = 0; it < 20000; ++it){   // watchdog: wedge -> fast absmax fail
    if (__hip_atomic_load(slot, __ATOMIC_RELAXED, __HIP_MEMORY_SCOPE_AGENT) >= target) break;
    __builtin_amdgcn_s_sleep(1);
  }
  __builtin_amdgcn_fence(__ATOMIC_ACQUIRE, "agent");  // buffer_inv
  __syncthreads();
}

// ---- pipelined single-panel GEMM segment via global_load_lds (R9-proven) --
// A-panel streamed in 64-col tiles (2 k-steps, 2KB/wave, 2 width-16 DMAs),
// triple-buffered, depth 3, counted vmcnt. LDS tile XOR-swizzled via
// pre-swizzled GLOBAL source (rule #21/m173): stage lane l covers row l>>3
// (+8 for DMA1), dest colb (l&7)*16, src colb ((l&7)^(l>>3))<<4. Reader
// (q,nl) k-step ks: byte nl*128 + ((ks*64 + q*16) ^ ((nl&7)<<4)).
#define STAGE_TILE(J, BUF)                                                     \
  {                                                                            \
    const char* g_ = pA + (size_t)(16 * wv + rl) * rbA + (size_t)(J) * 128 + scb; \
    char* d_ = ab0 + (BUF) * 8192;                                             \
    GLOAD_LDS16(g_, d_);                                                       \
    GLOAD_LDS16(g_ + (size_t)8 * rbA, d_ + 1024);                              \
  }

template<int NT>
__device__ __forceinline__ void gemm_phase(const char* pA, int rbA,
                                           const bf16_t* Wl, int woff, char* ab0,
                                           int wv, int lane, int q, int nl,
                                           f32x4& acc0, f32x4& acc1){
  const int rl  = lane >> 3;
  const int scb = ((lane & 7) ^ rl) << 4;
  const int swz = (nl & 7) << 4;
  STAGE_TILE(0, 0);
  if (NT > 1) STAGE_TILE(1, 1);
  if (NT > 2) STAGE_TILE(2, 2);
#pragma unroll
  for (int i = 0; i < NT; ++i){
    if      (i + 2 < NT) wait_vmcnt<4>();
    else if (i + 1 < NT) wait_vmcnt<2>();
    else                 wait_vmcnt<0>();
    __builtin_amdgcn_sched_barrier(0);
    const char* aw = ab0 + (i % 3) * 8192;
    bf16x8 a0 = *(const bf16x8*)(aw + nl * 128 + ((     q * 16) ^ swz));
    bf16x8 a1 = *(const bf16x8*)(aw + nl * 128 + ((64 + q * 16) ^ swz));
    bf16x8 w0 = *(const bf16x8*)(Wl + (size_t)(woff + 2 * i    ) * 512 + lane * 8);
    bf16x8 w1 = *(const bf16x8*)(Wl + (size_t)(woff + 2 * i + 1) * 512 + lane * 8);
    acc0 = __builtin_amdgcn_mfma_f32_16x16x32_bf16(a0, w0, acc0, 0, 0, 0);
    acc1 = __builtin_amdgcn_mfma_f32_16x16x32_bf16(a1, w1, acc1, 0, 0, 0);
    __builtin_amdgcn_sched_barrier(0);
    if (i + 3 < NT) STAGE_TILE(i + 3, i % 3);
  }
}

// fc variant: B-fragments from REGISTERS (wfc pinned via asm identity at init
// — R9's plain array was re-sunk to per-use global loads, VGPR stayed 132).
template<int NT>
__device__ __forceinline__ void fc_phase(const char* pA, int rbA,
                                         const bf16x8* wfc, char* ab0,
                                         int wv, int lane, int q, int nl,
                                         f32x4& acc0, f32x4& acc1){
  const int rl  = lane >> 3;
  const int scb = ((lane & 7) ^ rl) << 4;
  const int swz = (nl & 7) << 4;
  STAGE_TILE(0, 0);
  if (NT > 1) STAGE_TILE(1, 1);
  if (NT > 2) STAGE_TILE(2, 2);
#pragma unroll
  for (int i = 0; i < NT; ++i){
    if      (i + 2 < NT) wait_vmcnt<4>();
    else if (i + 1 < NT) wait_vmcnt<2>();
    else                 wait_vmcnt<0>();
    __builtin_amdgcn_sched_barrier(0);
    const char* aw = ab0 + (i % 3) * 8192;
    bf16x8 a0 = *(const bf16x8*)(aw + nl * 128 + ((     q * 16) ^ swz));
    bf16x8 a1 = *(const bf16x8*)(aw + nl * 128 + ((64 + q * 16) ^ swz));
    acc0 = __builtin_amdgcn_mfma_f32_16x16x32_bf16(a0, wfc[2 * i    ], acc0, 0, 0, 0);
    acc1 = __builtin_amdgcn_mfma_f32_16x16x32_bf16(a1, wfc[2 * i + 1], acc1, 0, 0, 0);
    __builtin_amdgcn_sched_barrier(0);
    if (i + 3 < NT) STAGE_TILE(i + 3, i % 3);
  }
}

// Persistent cooperative kernel: 256 blocks (1/CU) x 256 threads (4 waves).
// Block b owns hidden units {4b..4b+3} of both layers; fc cols {16b..16b+15}
// for b<32 (weights in pinned registers). Split-barrier schedule per step t
// (gens: H0=3t+2, H1=3t+3, T=3t+4; init=1):
//   P1a: h0-part of layer0 (dep: h0(t-1), fenced at H0(t-1) wait)
//   wait(T(t-1)) -> P1b token-part -> cell update -> store h0(t) -> arrive(H0)
//   P2a: h1-part of layer1 (dep: h1(t-1), fenced at/before T(t-1) wait)
//   wait(H0) -> P2b h0-part -> cell update -> store h1(t) -> arrive(H1)
//   b<32 : wait(H1) -> fc -> out + token(t+1) -> arrive(T)
//   b>=32: arrive(T) directly (monotone flag covers H1; token attested by b<32)
extern "C" __global__ void __launch_bounds__(NTHR, 1)
rnn_persistent(const float* __restrict__ hx,  const float* __restrict__ c0g,
               const float* __restrict__ Wih0, const float* __restrict__ Whh0,
               const float* __restrict__ bih0, const float* __restrict__ bhh0,
               const float* __restrict__ Wih1, const float* __restrict__ Whh1,
               const float* __restrict__ bih1, const float* __restrict__ bhh1,
               const float* __restrict__ fcw,  const float* __restrict__ fcb,
               float* __restrict__ out, void* ws)
{
  __shared__ bf16_t W0s[S0 * 512];          // 49152 B
  __shared__ bf16_t W1s[S1 * 512];          // 65536 B
  __shared__ bf16_t Abuf[3][4][1024];       // 24576 B
  __shared__ float  gates_s[4][16][17];
  __shared__ float  c0_l[BATCH][4];
  __shared__ float  c1_l[BATCH][4];
  __shared__ __align__(8) bf16_t hstage[BATCH][4];
  __shared__ __align__(8) bf16_t tstage[BATCH][16];
  __shared__ float  b0_l[16];
  __shared__ float  b1_l[16];
  __shared__ float  bf_l[16];

  const int b    = blockIdx.x;
  const int tid  = threadIdx.x;
  const int lane = tid & 63;
  const int wv   = tid >> 6;
  const int q    = lane >> 4;
  const int nl   = lane & 15;

  unsigned* arrive = (unsigned*)ws;
  bf16_t* token = (bf16_t*)((char*)ws + 32768);      // [64][512]
  bf16_t* h0b   = token + BATCH * INDIM;             // 2 x [64][1024]
  bf16_t* h1b   = h0b + 2 * BATCH * HDIM;            // 2 x [64][1024]

  char* ab0 = (char*)&Abuf[0][wv][0];

  // ---- init: weights fp32 -> bf16 into LDS (fragment order) ----
  for (int idx = tid; idx < S0 * 64; idx += NTHR){
    int s = idx >> 6, L = idx & 63;
    int qq = L >> 4, nn = L & 15;
    int col = (nn >> 2) * HDIM + b * 4 + (nn & 3);
    int k0 = s * 32 + qq * 8;
    const float* src = (k0 < INDIM) ? (Wih0 + col * INDIM + k0)
                                    : (Whh0 + col * HDIM + (k0 - INDIM));
    float4 u0 = ((const float4*)src)[0];
    float4 u1 = ((const float4*)src)[1];
    bf16_t* dst = W0s + idx * 8;
    dst[0]=(bf16_t)u0.x; dst[1]=(bf16_t)u0.y; dst[2]=(bf16_t)u0.z; dst[3]=(bf16_t)u0.w;
    dst[4]=(bf16_t)u1.x; dst[5]=(bf16_t)u1.y; dst[6]=(bf16_t)u1.z; dst[7]=(bf16_t)u1.w;
  }
  for (int idx = tid; idx < S1 * 64; idx += NTHR){
    int s = idx >> 6, L = idx & 63;
    int qq = L >> 4, nn = L & 15;
    int col = (nn >> 2) * HDIM + b * 4 + (nn & 3);
    int k0 = s * 32 + qq * 8;
    const float* src = (k0 < HDIM) ? (Wih1 + col * HDIM + k0)
                                   : (Whh1 + col * HDIM + (k0 - HDIM));
    float4 u0 = ((const float4*)src)[0];
    float4 u1 = ((const float4*)src)[1];
    bf16_t* dst = W1s + idx * 8;
    dst[0]=(bf16_t)u0.x; dst[1]=(bf16_t)u0.y; dst[2]=(bf16_t)u0.z; dst[3]=(bf16_t)u0.w;
    dst[4]=(bf16_t)u1.x; dst[5]=(bf16_t)u1.y; dst[6]=(bf16_t)u1.z; dst[7]=(bf16_t)u1.w;
  }
  // fc weights -> registers, PINNED with asm identity so the compiler cannot
  // re-sink the fcw loads into the loop (R9: VGPR stayed 132 = sunk).
  bf16x8 wfc[32];
  if (b < 32){
    const float* basew = fcw + (size_t)(b * 16 + nl) * HDIM + q * 8;
#pragma unroll
    for (int s = 0; s < 32; ++s){
      float4 u0 = *(const float4*)(basew + s * 32);
      float4 u1 = *(const float4*)(basew + s * 32 + 4);
      bf16_t t8[8] = {(bf16_t)u0.x,(bf16_t)u0.y,(bf16_t)u0.z,(bf16_t)u0.w,
                      (bf16_t)u1.x,(bf16_t)u1.y,(bf16_t)u1.z,(bf16_t)u1.w};
      wfc[s] = *(const bf16x8*)t8;
      asm volatile("" : "+v"(wfc[s]));   // opaque: no remat, no re-sink
    }
    if (tid < 16) bf_l[tid] = fcb[b * 16 + tid];
  }
  if (tid < 16){
    int col = (tid >> 2) * HDIM + b * 4 + (tid & 3);
    b0_l[tid] = bih0[col] + bhh0[col];
    b1_l[tid] = bih1[col] + bhh1[col];
  }
  {
    int row = tid & 63, uu = tid >> 6;
    int unit = b * 4 + uu;
    c0_l[row][uu] = c0g[row * HDIM + unit];
    c1_l[row][uu] = c0g[BATCH * HDIM + row * HDIM + unit];
  }
  if (tid < 64){
    int unit = b * 4;
    float4 v0 = *(const float4*)(hx + tid * HDIM + unit);
    float4 v1 = *(const float4*)(hx + BATCH * HDIM + tid * HDIM + unit);
    bf16_t p0[4] = {(bf16_t)v0.x, (bf16_t)v0.y, (bf16_t)v0.z, (bf16_t)v0.w};
    bf16_t p1[4] = {(bf16_t)v1.x, (bf16_t)v1.y, (bf16_t)v1.z, (bf16_t)v1.w};
    __hip_atomic_store((unsigned long long*)(h0b + tid * HDIM + unit),
                       *(const unsigned long long*)p0, __ATOMIC_RELAXED, __HIP_MEMORY_SCOPE_AGENT);
    __hip_atomic_store((unsigned long long*)(h1b + tid * HDIM + unit),
                       *(const unsigned long long*)p1, __ATOMIC_RELAXED, __HIP_MEMORY_SCOPE_AGENT);
  }
  if (tid < 32){
    __hip_atomic_store((unsigned long long*)(token + b * 128 + tid * 4), 0ull,
                       __ATOMIC_RELAXED, __HIP_MEMORY_SCOPE_AGENT);
  }

  bar_arrive(arrive, 1);
  bar_wait(arrive, 1);

#pragma unroll 1
  for (int t = 0; t < TSTEPS; ++t){
    const unsigned g  = 3u * (unsigned)t;
    const unsigned gTprev = g + 1, gH0 = g + 2, gH1 = g + 3, gT = g + 4;
    const int rp = t & 1, wp = rp ^ 1;
    const bf16_t* h0r = h0b + rp * BATCH * HDIM;
    bf16_t*       h0w = h0b + wp * BATCH * HDIM;
    const bf16_t* h1r = h1b + rp * BATCH * HDIM;
    bf16_t*       h1w = h1b + wp * BATCH * HDIM;

    // ---- phase 1: layer-0 gates ----
    {
      f32x4 acc0 = {0.f,0.f,0.f,0.f}, acc1 = {0.f,0.f,0.f,0.f};
      // independent half: h0(t-1) part (k-steps 16..47)
      gemm_phase<16>((const char*)h0r, 2048, W0s, 16, ab0, wv, lane, q, nl, acc0, acc1);
      bar_wait(arrive, gTprev);            // token(t) published
      // dependent half: token part (k-steps 0..15)
      gemm_phase<8>((const char*)token, 1024, W0s, 0, ab0, wv, lane, q, nl, acc0, acc1);
      f32x4 accv = acc0 + acc1;
      float bias = b0_l[nl];
#pragma unroll
      for (int r = 0; r < 4; ++r) gates_s[wv][q * 4 + r][nl] = accv[r] + bias;
      __syncthreads();
      int row = tid & 63, uu = tid >> 6;
      float pi = gates_s[row >> 4][row & 15][0 * 4 + uu];
      float pf = gates_s[row >> 4][row & 15][1 * 4 + uu];
      float pg = gates_s[row >> 4][row & 15][2 * 4 + uu];
      float po = gates_s[row >> 4][row & 15][3 * 4 + uu];
      float ig = fast_sigmoid(pi), fg = fast_sigmoid(pf);
      float gg = fast_tanh(pg),    og = fast_sigmoid(po);
      float c  = fg * c0_l[row][uu] + ig * gg;
      c0_l[row][uu] = c;
      hstage[row][uu] = (bf16_t)(og * fast_tanh(c));
      __syncthreads();
      if (tid < 64){
        unsigned long long v = *(const unsigned long long*)hstage[tid];
        __hip_atomic_store((unsigned long long*)(h0w + tid * HDIM + b * 4), v,
                           __ATOMIC_RELAXED, __HIP_MEMORY_SCOPE_AGENT);
      }
    }
    bar_arrive(arrive, gH0);

    // ---- phase 2: layer-1 gates ----
    {
      f32x4 acc0 = {0.f,0.f,0.f,0.f}, acc1 = {0.f,0.f,0.f,0.f};
      // independent half: h1(t-1) part (k-steps 32..63)
      gemm_phase<16>((const char*)h1r, 2048, W1s, 32, ab0, wv, lane, q, nl, acc0, acc1);
      bar_wait(arrive, gH0);               // h0(t) published
      // dependent half: h0(t) part (k-steps 0..31)
      gemm_phase<16>((const char*)h0w, 2048, W1s, 0, ab0, wv, lane, q, nl, acc0, acc1);
      f32x4 accv = acc0 + acc1;
      float bias = b1_l[nl];
#pragma unroll
      for (int r = 0; r < 4; ++r) gates_s[wv][q * 4 + r][nl] = accv[r] + bias;
      __syncthreads();
      int row = tid & 63, uu = tid >> 6;
      float pi = gates_s[row >> 4][row & 15][0 * 4 + uu];
      float pf = gates_s[row >> 4][row & 15][1 * 4 + uu];
      float pg = gates_s[row >> 4][row & 15][2 * 4 + uu];
      float po = gates_s[row >> 4][row & 15][3 * 4 + uu];
      float ig = fast_sigmoid(pi), fg = fast_sigmoid(pf);
      float gg = fast_tanh(pg),    og = fast_sigmoid(po);
      float c  = fg * c1_l[row][uu] + ig * gg;
      c1_l[row][uu] = c;
      hstage[row][uu] = (bf16_t)(og * fast_tanh(c));
      __syncthreads();
      if (tid < 64){
        unsigned long long v = *(const unsigned long long*)hstage[tid];
        __hip_atomic_store((unsigned long long*)(h1w + tid * HDIM + b * 4), v,
                           __ATOMIC_RELAXED, __HIP_MEMORY_SCOPE_AGENT);
      }
    }
    bar_arrive(arrive, gH1);

    // ---- phase 3: fc (blocks 0..31); others signal T and run ahead ----
    if (b < 32){
      bar_wait(arrive, gH1);               // h1(t) published
      f32x4 acc0 = {0.f,0.f,0.f,0.f}, acc1 = {0.f,0.f,0.f,0.f};
      fc_phase<16>((const char*)h1w, 2048, wfc, ab0, wv, lane, q, nl, acc0, acc1);
      f32x4 accv = acc0 + acc1;
      int col = b * 16 + nl;
      float bias = bf_l[nl];
#pragma unroll
      for (int r = 0; r < 4; ++r){
        int m = wv * 16 + q * 4 + r;
        float v = fast_sigmoid(accv[r] + bias);
        out[m * (TSTEPS * INDIM) + t * INDIM + col] = v;
        tstage[m][nl] = (bf16_t)v;
      }
      __syncthreads();
      {
        int row = tid >> 2, part = tid & 3;
        unsigned long long v = *(const unsigned long long*)&tstage[row][part * 4];
        __hip_atomic_store((unsigned long long*)(token + row * INDIM + b * 16 + part * 4), v,
                           __ATOMIC_RELAXED, __HIP_MEMORY_SCOPE_AGENT);
      }
    }
    bar_arrive(arrive, gT);                // b>=32 jump H1->T (monotone flag)
  }
}

extern "C" void kernel_launch(void* const* d_in, const int* in_sizes, int n_in,
                              void* d_out, int out_size, void* d_ws, size_t ws_size,
                              hipStream_t stream){
  const float* hx   = (const float*)d_in[1];
  const float* c0g  = (const float*)d_in[2];
  const float* Wih0 = (const float*)d_in[3];
  const float* Whh0 = (const float*)d_in[4];
  const float* bih0 = (const float*)d_in[5];
  const float* bhh0 = (const float*)d_in[6];
  const float* Wih1 = (const float*)d_in[7];
  const float* Whh1 = (const float*)d_in[8];
  const float* bih1 = (const float*)d_in[9];
  const float* bhh1 = (const float*)d_in[10];
  const float* fcw  = (const float*)d_in[11];
  const float* fcb  = (const float*)d_in[12];
  float* out = (float*)d_out;

  hipMemsetAsync(d_ws, 0, 32768, stream);

  void* args[] = { (void*)&hx, (void*)&c0g, (void*)&Wih0, (void*)&Whh0,
                   (void*)&bih0, (void*)&bhh0, (void*)&Wih1, (void*)&Whh1,
                   (void*)&bih1, (void*)&bhh1, (void*)&fcw, (void*)&fcb,
                   (void*)&out, (void*)&d_ws };
  hipLaunchCooperativeKernel((const void*)rnn_persistent, dim3(NBLK), dim3(NTHR),
                             args, 0, stream);
}

// Round 11
// 6760.799 us; speedup vs baseline: 2.1586x; 1.0331x over previous
//
#include <hip/hip_runtime.h>

#define BATCH 64
#define TSTEPS 256
#define INDIM 512
#define HDIM 1024
#define NBLK 256
#define NTHR 256
#define S0 48   // (512+1024)/32 k-steps, layer0
#define S1 64   // 2048/32, layer1

typedef __bf16 bf16_t;
typedef __bf16 bf16x8 __attribute__((ext_vector_type(8)));
typedef float  f32x4  __attribute__((ext_vector_type(4)));

typedef const __attribute__((address_space(1))) void gas_t;
typedef __attribute__((address_space(3))) void las_t;
#define GLOAD_LDS16(g, l) \
  __builtin_amdgcn_global_load_lds((gas_t*)(g), (las_t*)(l), 16, 0, 0)

__device__ __forceinline__ float fast_sigmoid(float x){
  x = fminf(fmaxf(x, -30.f), 30.f);
  return 1.f / (1.f + __expf(-x));
}
__device__ __forceinline__ float fast_tanh(float x){
  x = fminf(fmaxf(x, -15.f), 15.f);
  float e = __expf(2.f * x);
  return (e - 1.f) / (e + 1.f);
}

template<int N>
__device__ __forceinline__ void wait_vmcnt(){
  asm volatile("s_waitcnt vmcnt(%0)" :: "n"(N) : "memory");
}

// ---- split grid barrier (R10-proven): arrive early, wait late ------------
__device__ __forceinline__ void bar_arrive(unsigned* arrive, unsigned target){
  asm volatile("s_waitcnt vmcnt(0)" ::: "memory");
  __syncthreads();
  if (threadIdx.x == 0)
    __hip_atomic_store(&arrive[blockIdx.x * 16], target, __ATOMIC_RELAXED, __HIP_MEMORY_SCOPE_AGENT);
}
__device__ __forceinline__ void bar_wait(unsigned* arrive, unsigned target){
  unsigned* slot = &arrive[threadIdx.x * 16];
  for (int it = 0; it < 20000; ++it){   // watchdog: wedge -> fast absmax fail
    if (__hip_atomic_load(slot, __ATOMIC_RELAXED, __HIP_MEMORY_SCOPE_AGENT) >= target) break;
    __builtin_amdgcn_s_sleep(1);
  }
  __builtin_amdgcn_fence(__ATOMIC_ACQUIRE, "agent");  // buffer_inv
  __syncthreads();
}

// ---- pipelined GEMM segment via global_load_lds ---------------------------
// R11 changes vs R10 (which measured rate ~RTT/3 ≈ 400-500cy/tile under the
// post-inv all-block burst): (1) depth 4 with FIVE 8KB buffers — rate floor
// RTT/4; (2) refill-early: tile i+4's DMAs issue right after the wait,
// BEFORE tile i's ds_read/MFMA, adding iteration compute to the latency
// budget. Rotation safety: live tiles i..i+3 occupy bufs i%5..(i+3)%5, the
// refill writes (i+4)%5 — always disjoint; its data is consumed only after
// iteration i+4's wait (vmcnt<=6 => tile i+4 landed).
// LDS tile swizzle (R9-proven, rule #21/m173): stage lane l covers row l>>3
// (+8 for DMA1), dest colb (l&7)*16, src colb ((l&7)^(l>>3))<<4; reader
// (q,nl) k-step ks: byte nl*128 + ((ks*64 + q*16) ^ ((nl&7)<<4)).
#define STAGE_TILE(J, BUF)                                                     \
  {                                                                            \
    const char* g_ = pA + (size_t)(16 * wv + rl) * rbA + (size_t)(J) * 128 + scb; \
    char* d_ = ab0 + (BUF) * 8192;                                             \
    GLOAD_LDS16(g_, d_);                                                       \
    GLOAD_LDS16(g_ + (size_t)8 * rbA, d_ + 1024);                              \
  }

template<int NT>
__device__ __forceinline__ void gemm_phase(const char* pA, int rbA,
                                           const bf16_t* Wl, int woff, char* ab0,
                                           int wv, int lane, int q, int nl,
                                           f32x4& acc0, f32x4& acc1){
  const int rl  = lane >> 3;
  const int scb = ((lane & 7) ^ rl) << 4;
  const int swz = (nl & 7) << 4;
  STAGE_TILE(0, 0);
  if (NT > 1) STAGE_TILE(1, 1);
  if (NT > 2) STAGE_TILE(2, 2);
  if (NT > 3) STAGE_TILE(3, 3);
#pragma unroll
  for (int i = 0; i < NT; ++i){
    const int rem = NT - 1 - i;
    if      (rem >= 3) wait_vmcnt<6>();
    else if (rem == 2) wait_vmcnt<4>();
    else if (rem == 1) wait_vmcnt<2>();
    else               wait_vmcnt<0>();
    __builtin_amdgcn_sched_barrier(0);
    if (i + 4 < NT) STAGE_TILE(i + 4, (i + 4) % 5)   // refill-early
    const char* aw = ab0 + (i % 5) * 8192;
    bf16x8 a0 = *(const bf16x8*)(aw + nl * 128 + ((     q * 16) ^ swz));
    bf16x8 a1 = *(const bf16x8*)(aw + nl * 128 + ((64 + q * 16) ^ swz));
    bf16x8 w0 = *(const bf16x8*)(Wl + (size_t)(woff + 2 * i    ) * 512 + lane * 8);
    bf16x8 w1 = *(const bf16x8*)(Wl + (size_t)(woff + 2 * i + 1) * 512 + lane * 8);
    acc0 = __builtin_amdgcn_mfma_f32_16x16x32_bf16(a0, w0, acc0, 0, 0, 0);
    acc1 = __builtin_amdgcn_mfma_f32_16x16x32_bf16(a1, w1, acc1, 0, 0, 0);
  }
}

// fc variant: B-fragments from the wfc array (compiler reloads from L2/MALL;
// pinning attempts failed in R9/R10 — VGPR stayed 132 — but plain clustered
// reloads measured acceptable).
template<int NT>
__device__ __forceinline__ void fc_phase(const char* pA, int rbA,
                                         const bf16x8* wfc, char* ab0,
                                         int wv, int lane, int q, int nl,
                                         f32x4& acc0, f32x4& acc1){
  const int rl  = lane >> 3;
  const int scb = ((lane & 7) ^ rl) << 4;
  const int swz = (nl & 7) << 4;
  STAGE_TILE(0, 0);
  if (NT > 1) STAGE_TILE(1, 1);
  if (NT > 2) STAGE_TILE(2, 2);
  if (NT > 3) STAGE_TILE(3, 3);
#pragma unroll
  for (int i = 0; i < NT; ++i){
    const int rem = NT - 1 - i;
    if      (rem >= 3) wait_vmcnt<6>();
    else if (rem == 2) wait_vmcnt<4>();
    else if (rem == 1) wait_vmcnt<2>();
    else               wait_vmcnt<0>();
    __builtin_amdgcn_sched_barrier(0);
    if (i + 4 < NT) STAGE_TILE(i + 4, (i + 4) % 5)
    const char* aw = ab0 + (i % 5) * 8192;
    bf16x8 a0 = *(const bf16x8*)(aw + nl * 128 + ((     q * 16) ^ swz));
    bf16x8 a1 = *(const bf16x8*)(aw + nl * 128 + ((64 + q * 16) ^ swz));
    acc0 = __builtin_amdgcn_mfma_f32_16x16x32_bf16(a0, wfc[2 * i    ], acc0, 0, 0, 0);
    acc1 = __builtin_amdgcn_mfma_f32_16x16x32_bf16(a1, wfc[2 * i + 1], acc1, 0, 0, 0);
  }
}

// Persistent cooperative kernel: 256 blocks (1/CU) x 256 threads (4 waves).
// Split-barrier schedule per step t (gens: H0=3t+2, H1=3t+3, T=3t+4; init=1):
//   P1a (h0(t-1), 16 tiles) -> wait(T(t-1)) -> P1b (token, 8) -> cell0 -> arrive(H0)
//   P2a (h1(t-1), 16) -> wait(H0) -> P2b (h0(t), 16) -> cell1 -> arrive(H1)
//   b<32: wait(H1) -> fc (16) -> out+token -> arrive(T);  b>=32: arrive(T)
extern "C" __global__ void __launch_bounds__(NTHR, 1)
rnn_persistent(const float* __restrict__ hx,  const float* __restrict__ c0g,
               const float* __restrict__ Wih0, const float* __restrict__ Whh0,
               const float* __restrict__ bih0, const float* __restrict__ bhh0,
               const float* __restrict__ Wih1, const float* __restrict__ Whh1,
               const float* __restrict__ bih1, const float* __restrict__ bhh1,
               const float* __restrict__ fcw,  const float* __restrict__ fcb,
               float* __restrict__ out, void* ws)
{
  __shared__ bf16_t W0s[S0 * 512];          // 49152 B
  __shared__ bf16_t W1s[S1 * 512];          // 65536 B
  __shared__ bf16_t Abuf[5][4][1024];       // 40960 B: 5 bufs x 4 waves x 2KB
  __shared__ float  gates_s[4][16][17];     // 4352 B (tstage OVERLAYS this)
  __shared__ float  c0_l[BATCH][4];
  __shared__ float  c1_l[BATCH][4];
  __shared__ __align__(8) bf16_t hstage[BATCH][4];
  __shared__ float  b0_l[16];
  __shared__ float  b1_l[16];
  __shared__ float  bf_l[16];
  // tstage overlay: gates_s is idle from P2-epilogue sync until P1(t+1);
  // fc uses this window, separated by __syncthreads on both sides.
  bf16_t (*tstage)[16] = (bf16_t (*)[16])&gates_s[0][0][0];   // 2048 B

  const int b    = blockIdx.x;
  const int tid  = threadIdx.x;
  const int lane = tid & 63;
  const int wv   = tid >> 6;
  const int q    = lane >> 4;
  const int nl   = lane & 15;

  unsigned* arrive = (unsigned*)ws;
  bf16_t* token = (bf16_t*)((char*)ws + 32768);      // [64][512]
  bf16_t* h0b   = token + BATCH * INDIM;             // 2 x [64][1024]
  bf16_t* h1b   = h0b + 2 * BATCH * HDIM;            // 2 x [64][1024]

  char* ab0 = (char*)&Abuf[0][wv][0];

  // ---- init: weights fp32 -> bf16 into LDS (fragment order) ----
  for (int idx = tid; idx < S0 * 64; idx += NTHR){
    int s = idx >> 6, L = idx & 63;
    int qq = L >> 4, nn = L & 15;
    int col = (nn >> 2) * HDIM + b * 4 + (nn & 3);
    int k0 = s * 32 + qq * 8;
    const float* src = (k0 < INDIM) ? (Wih0 + col * INDIM + k0)
                                    : (Whh0 + col * HDIM + (k0 - INDIM));
    float4 u0 = ((const float4*)src)[0];
    float4 u1 = ((const float4*)src)[1];
    bf16_t* dst = W0s + idx * 8;
    dst[0]=(bf16_t)u0.x; dst[1]=(bf16_t)u0.y; dst[2]=(bf16_t)u0.z; dst[3]=(bf16_t)u0.w;
    dst[4]=(bf16_t)u1.x; dst[5]=(bf16_t)u1.y; dst[6]=(bf16_t)u1.z; dst[7]=(bf16_t)u1.w;
  }
  for (int idx = tid; idx < S1 * 64; idx += NTHR){
    int s = idx >> 6, L = idx & 63;
    int qq = L >> 4, nn = L & 15;
    int col = (nn >> 2) * HDIM + b * 4 + (nn & 3);
    int k0 = s * 32 + qq * 8;
    const float* src = (k0 < HDIM) ? (Wih1 + col * HDIM + k0)
                                   : (Whh1 + col * HDIM + (k0 - HDIM));
    float4 u0 = ((const float4*)src)[0];
    float4 u1 = ((const float4*)src)[1];
    bf16_t* dst = W1s + idx * 8;
    dst[0]=(bf16_t)u0.x; dst[1]=(bf16_t)u0.y; dst[2]=(bf16_t)u0.z; dst[3]=(bf16_t)u0.w;
    dst[4]=(bf16_t)u1.x; dst[5]=(bf16_t)u1.y; dst[6]=(bf16_t)u1.z; dst[7]=(bf16_t)u1.w;
  }
  bf16x8 wfc[32];
  if (b < 32){
    const float* basew = fcw + (size_t)(b * 16 + nl) * HDIM + q * 8;
#pragma unroll
    for (int s = 0; s < 32; ++s){
      float4 u0 = *(const float4*)(basew + s * 32);
      float4 u1 = *(const float4*)(basew + s * 32 + 4);
      bf16_t t8[8] = {(bf16_t)u0.x,(bf16_t)u0.y,(bf16_t)u0.z,(bf16_t)u0.w,
                      (bf16_t)u1.x,(bf16_t)u1.y,(bf16_t)u1.z,(bf16_t)u1.w};
      wfc[s] = *(const bf16x8*)t8;
    }
    if (tid < 16) bf_l[tid] = fcb[b * 16 + tid];
  }
  if (tid < 16){
    int col = (tid >> 2) * HDIM + b * 4 + (tid & 3);
    b0_l[tid] = bih0[col] + bhh0[col];
    b1_l[tid] = bih1[col] + bhh1[col];
  }
  {
    int row = tid & 63, uu = tid >> 6;
    int unit = b * 4 + uu;
    c0_l[row][uu] = c0g[row * HDIM + unit];
    c1_l[row][uu] = c0g[BATCH * HDIM + row * HDIM + unit];
  }
  if (tid < 64){
    int unit = b * 4;
    float4 v0 = *(const float4*)(hx + tid * HDIM + unit);
    float4 v1 = *(const float4*)(hx + BATCH * HDIM + tid * HDIM + unit);
    bf16_t p0[4] = {(bf16_t)v0.x, (bf16_t)v0.y, (bf16_t)v0.z, (bf16_t)v0.w};
    bf16_t p1[4] = {(bf16_t)v1.x, (bf16_t)v1.y, (bf16_t)v1.z, (bf16_t)v1.w};
    __hip_atomic_store((unsigned long long*)(h0b + tid * HDIM + unit),
                       *(const unsigned long long*)p0, __ATOMIC_RELAXED, __HIP_MEMORY_SCOPE_AGENT);
    __hip_atomic_store((unsigned long long*)(h1b + tid * HDIM + unit),
                       *(const unsigned long long*)p1, __ATOMIC_RELAXED, __HIP_MEMORY_SCOPE_AGENT);
  }
  if (tid < 32){
    __hip_atomic_store((unsigned long long*)(token + b * 128 + tid * 4), 0ull,
                       __ATOMIC_RELAXED, __HIP_MEMORY_SCOPE_AGENT);
  }

  bar_arrive(arrive, 1);
  bar_wait(arrive, 1);

#pragma unroll 1
  for (int t = 0; t < TSTEPS; ++t){
    const unsigned g  = 3u * (unsigned)t;
    const unsigned gTprev = g + 1, gH0 = g + 2, gH1 = g + 3, gT = g + 4;
    const int rp = t & 1, wp = rp ^ 1;
    const bf16_t* h0r = h0b + rp * BATCH * HDIM;
    bf16_t*       h0w = h0b + wp * BATCH * HDIM;
    const bf16_t* h1r = h1b + rp * BATCH * HDIM;
    bf16_t*       h1w = h1b + wp * BATCH * HDIM;

    // ---- phase 1: layer-0 gates ----
    {
      f32x4 acc0 = {0.f,0.f,0.f,0.f}, acc1 = {0.f,0.f,0.f,0.f};
      gemm_phase<16>((const char*)h0r, 2048, W0s, 16, ab0, wv, lane, q, nl, acc0, acc1);
      bar_wait(arrive, gTprev);            // token(t) published
      gemm_phase<8>((const char*)token, 1024, W0s, 0, ab0, wv, lane, q, nl, acc0, acc1);
      f32x4 accv = acc0 + acc1;
      float bias = b0_l[nl];
#pragma unroll
      for (int r = 0; r < 4; ++r) gates_s[wv][q * 4 + r][nl] = accv[r] + bias;
      __syncthreads();
      int row = tid & 63, uu = tid >> 6;
      float pi = gates_s[row >> 4][row & 15][0 * 4 + uu];
      float pf = gates_s[row >> 4][row & 15][1 * 4 + uu];
      float pg = gates_s[row >> 4][row & 15][2 * 4 + uu];
      float po = gates_s[row >> 4][row & 15][3 * 4 + uu];
      float ig = fast_sigmoid(pi), fg = fast_sigmoid(pf);
      float gg = fast_tanh(pg),    og = fast_sigmoid(po);
      float c  = fg * c0_l[row][uu] + ig * gg;
      c0_l[row][uu] = c;
      hstage[row][uu] = (bf16_t)(og * fast_tanh(c));
      __syncthreads();
      if (tid < 64){
        unsigned long long v = *(const unsigned long long*)hstage[tid];
        __hip_atomic_store((unsigned long long*)(h0w + tid * HDIM + b * 4), v,
                           __ATOMIC_RELAXED, __HIP_MEMORY_SCOPE_AGENT);
      }
    }
    bar_arrive(arrive, gH0);

    // ---- phase 2: layer-1 gates ----
    {
      f32x4 acc0 = {0.f,0.f,0.f,0.f}, acc1 = {0.f,0.f,0.f,0.f};
      gemm_phase<16>((const char*)h1r, 2048, W1s, 32, ab0, wv, lane, q, nl, acc0, acc1);
      bar_wait(arrive, gH0);               // h0(t) published
      gemm_phase<16>((const char*)h0w, 2048, W1s, 0, ab0, wv, lane, q, nl, acc0, acc1);
      f32x4 accv = acc0 + acc1;
      float bias = b1_l[nl];
#pragma unroll
      for (int r = 0; r < 4; ++r) gates_s[wv][q * 4 + r][nl] = accv[r] + bias;
      __syncthreads();
      int row = tid & 63, uu = tid >> 6;
      float pi = gates_s[row >> 4][row & 15][0 * 4 + uu];
      float pf = gates_s[row >> 4][row & 15][1 * 4 + uu];
      float pg = gates_s[row >> 4][row & 15][2 * 4 + uu];
      float po = gates_s[row >> 4][row & 15][3 * 4 + uu];
      float ig = fast_sigmoid(pi), fg = fast_sigmoid(pf);
      float gg = fast_tanh(pg),    og = fast_sigmoid(po);
      float c  = fg * c1_l[row][uu] + ig * gg;
      c1_l[row][uu] = c;
      hstage[row][uu] = (bf16_t)(og * fast_tanh(c));
      __syncthreads();
      if (tid < 64){
        unsigned long long v = *(const unsigned long long*)hstage[tid];
        __hip_atomic_store((unsigned long long*)(h1w + tid * HDIM + b * 4), v,
                           __ATOMIC_RELAXED, __HIP_MEMORY_SCOPE_AGENT);
      }
    }
    bar_arrive(arrive, gH1);

    // ---- phase 3: fc (blocks 0..31); others signal T and run ahead ----
    if (b < 32){
      bar_wait(arrive, gH1);               // h1(t) published
      f32x4 acc0 = {0.f,0.f,0.f,0.f}, acc1 = {0.f,0.f,0.f,0.f};
      fc_phase<16>((const char*)h1w, 2048, wfc, ab0, wv, lane, q, nl, acc0, acc1);
      f32x4 accv = acc0 + acc1;
      int col = b * 16 + nl;
      float bias = bf_l[nl];
#pragma unroll
      for (int r = 0; r < 4; ++r){
        int m = wv * 16 + q * 4 + r;
        float v = fast_sigmoid(accv[r] + bias);
        out[m * (TSTEPS * INDIM) + t * INDIM + col] = v;
        tstage[m][nl] = (bf16_t)v;
      }
      __syncthreads();
      {
        int row = tid >> 2, part = tid & 3;
        unsigned long long v = *(const unsigned long long*)&tstage[row][part * 4];
        __hip_atomic_store((unsigned long long*)(token + row * INDIM + b * 16 + part * 4), v,
                           __ATOMIC_RELAXED, __HIP_MEMORY_SCOPE_AGENT);
      }
      __syncthreads();                     // tstage (gates_s overlay) free again
    }
    bar_arrive(arrive, gT);                // b>=32 jump H1->T (monotone flag)
  }
}

extern "C" void kernel_launch(void* const* d_in, const int* in_sizes, int n_in,
                              void* d_out, int out_size, void* d_ws, size_t ws_size,
                              hipStream_t stream){
  const float* hx   = (const float*)d_in[1];
  const float* c0g  = (const float*)d_in[2];
  const float* Wih0 = (const float*)d_in[3];
  const float* Whh0 = (const float*)d_in[4];
  const float* bih0 = (const float*)d_in[5];
  const float* bhh0 = (const float*)d_in[6];
  const float* Wih1 = (const float*)d_in[7];
  const float* Whh1 = (const float*)d_in[8];
  const float* bih1 = (const float*)d_in[9];
  const float* bhh1 = (const float*)d_in[10];
  const float* fcw  = (const float*)d_in[11];
  const float* fcb  = (const float*)d_in[12];
  float* out = (float*)d_out;

  hipMemsetAsync(d_ws, 0, 32768, stream);

  void* args[] = { (void*)&hx, (void*)&c0g, (void*)&Wih0, (void*)&Whh0,
                   (void*)&bih0, (void*)&bhh0, (void*)&Wih1, (void*)&Whh1,
                   (void*)&bih1, (void*)&bhh1, (void*)&fcw, (void*)&fcb,
                   (void*)&out, (void*)&d_ws };
  hipLaunchCooperativeKernel((const void*)rnn_persistent, dim3(NBLK), dim3(NTHR),
                             args, 0, stream);
}